// Round 1
// baseline (3233.154 us; speedup 1.0000x reference)
//
#include <hip/hip_runtime.h>
#include <math.h>
#include <float.h>

#define NN 100000
#define NE 1600000
#define ETOT 1700000   // NE + NN self loops
#define DIN 264
#define DH 64
#define SLOPE 0.2f

__global__ void k_mean(const float* __restrict__ ea, float* __restrict__ sum) {
  float acc = 0.f;
  for (int i = blockIdx.x * blockDim.x + threadIdx.x; i < NE; i += gridDim.x * blockDim.x)
    acc += ea[i];
  #pragma unroll
  for (int off = 32; off > 0; off >>= 1) acc += __shfl_xor(acc, off);
  __shared__ float s[4];
  int lane = threadIdx.x & 63, w = threadIdx.x >> 6;
  if (lane == 0) s[w] = acc;
  __syncthreads();
  if (threadIdx.x == 0) atomicAdd(sum, s[0] + s[1] + s[2] + s[3]);
}

__global__ void k_hist(const int* __restrict__ ei, unsigned* __restrict__ deg) {
  int e = blockIdx.x * blockDim.x + threadIdx.x;
  if (e >= ETOT) return;
  int d = (e < NE) ? ei[NE + e] : e - NE;
  atomicAdd(&deg[d], 1u);
}

// single-block exclusive scan of deg -> rowptr (and wptr cursor copy)
__global__ void k_scan(const unsigned* __restrict__ deg, unsigned* __restrict__ rowptr,
                       unsigned* __restrict__ wptr) {
  __shared__ unsigned ls[1024];
  const int CH = (NN + 1023) / 1024;  // 98
  int t = threadIdx.x;
  int beg = t * CH, end = min(beg + CH, NN);
  unsigned s = 0;
  for (int i = beg; i < end; i++) s += deg[i];
  ls[t] = s;
  __syncthreads();
  for (int off = 1; off < 1024; off <<= 1) {
    unsigned v = (t >= off) ? ls[t - off] : 0u;
    __syncthreads();
    ls[t] += v;
    __syncthreads();
  }
  unsigned base = (t == 0) ? 0u : ls[t - 1];
  for (int i = beg; i < end; i++) {
    rowptr[i] = base;
    wptr[i] = base;
    base += deg[i];
  }
  if (t == 1023) rowptr[NN] = ls[1023];
}

__global__ void k_scatter(const int* __restrict__ ei, const float* __restrict__ ea,
                          const float* __restrict__ sump, unsigned* __restrict__ wptr,
                          int2* __restrict__ csr) {
  int e = blockIdx.x * blockDim.x + threadIdx.x;
  if (e >= ETOT) return;
  int s, d;
  float a;
  if (e < NE) {
    s = ei[e];
    d = ei[NE + e];
    a = ea[e];
  } else {
    s = d = e - NE;
    a = sump[0] * (1.0f / NE);
  }
  unsigned pos = atomicAdd(&wptr[d], 1u);
  csr[pos] = make_int2(s, __float_as_int(a));
}

// One wave computes 16 nodes x 64 dims for TWO weight matrices (Wl, Wr).
// X loads: coalesced 128B per 8-lane group; values broadcast to lanes via shfl.
// __launch_bounds__(256,4): 128-VGPR budget -> acc[32]+xv[8] stay in registers
// (the previous 64-VGPR default cap spilled them: WRITE_SIZE was 27x the output).
template <int K>
__global__ __launch_bounds__(256, 4)
void k_gemm2(const float* __restrict__ X,
             const float* __restrict__ Wl, const float* __restrict__ bl,
             const float* __restrict__ Wr, const float* __restrict__ br,
             float* __restrict__ xl, float* __restrict__ xr) {
  int wave = (blockIdx.x * blockDim.x + threadIdx.x) >> 6;
  int lane = threadIdx.x & 63;
  int n0 = wave * 16;  // NN % 16 == 0, exact; last block's spare waves exit
  if (n0 >= NN) return;
  int lrow = lane >> 3;        // which of 8 rows this lane helps load
  int lcol = (lane & 7) * 4;   // float4 offset within a 32-col chunk
  float accl[16], accr[16];
  #pragma unroll
  for (int m = 0; m < 16; m++) { accl[m] = 0.f; accr[m] = 0.f; }
  constexpr int KBF = (K / 32) * 32;
  for (int kb = 0; kb < KBF; kb += 32) {
    float4 xv0 = *(const float4*)&X[(n0 + lrow) * K + kb + lcol];
    float4 xv1 = *(const float4*)&X[(n0 + 8 + lrow) * K + kb + lcol];
    #pragma unroll
    for (int kk = 0; kk < 32; kk++) {
      float wl = Wl[(kb + kk) * DH + lane];
      float wr = Wr[(kb + kk) * DH + lane];
      #pragma unroll
      for (int m = 0; m < 8; m++) {
        float bx0 = __shfl((&xv0.x)[kk & 3], m * 8 + (kk >> 2));
        accl[m] = fmaf(bx0, wl, accl[m]);
        accr[m] = fmaf(bx0, wr, accr[m]);
        float bx1 = __shfl((&xv1.x)[kk & 3], m * 8 + (kk >> 2));
        accl[m + 8] = fmaf(bx1, wl, accl[m + 8]);
        accr[m + 8] = fmaf(bx1, wr, accr[m + 8]);
      }
    }
  }
  // tail columns (K=264 -> 8 cols): W tail held in regs, X rows broadcast-loaded
  constexpr int KT = K - KBF;
  if constexpr (KT > 0) {
    float wtl[KT], wtr[KT];
    #pragma unroll
    for (int kk = 0; kk < KT; kk++) {
      wtl[kk] = Wl[(KBF + kk) * DH + lane];
      wtr[kk] = Wr[(KBF + kk) * DH + lane];
    }
    #pragma unroll
    for (int m = 0; m < 16; m++) {
      const float* xp = &X[(n0 + m) * K + KBF];
      #pragma unroll
      for (int kk = 0; kk < KT; kk++) {
        float xc = xp[kk];  // wave-uniform address -> broadcast load
        accl[m] = fmaf(xc, wtl[kk], accl[m]);
        accr[m] = fmaf(xc, wtr[kk], accr[m]);
      }
    }
  }
  #pragma unroll
  for (int m = 0; m < 16; m++) {
    xl[(n0 + m) * DH + lane] = accl[m] + bl[lane];
    xr[(n0 + m) * DH + lane] = accr[m] + br[lane];
  }
}

// Fused per-node attention: 16 lanes own one dst node; online softmax + max-aggregate.
// Edge loop: cooperative coalesced csr chunk loads + 4-edge gather batches.
// HEAD=true additionally computes out[n] = relu(h@W3+b3)@W4+b4 (no h write).
template <bool HEAD>
__global__ void k_attn(const unsigned* __restrict__ rowptr, const int2* __restrict__ csr,
                       const float* __restrict__ xl, const float* __restrict__ xr,
                       const float* __restrict__ We, const float* __restrict__ att,
                       const float* __restrict__ bias, float* __restrict__ h,
                       const float* __restrict__ W3, const float* __restrict__ b3,
                       const float* __restrict__ W4, const float* __restrict__ b4,
                       float* __restrict__ out) {
  int n = (blockIdx.x * blockDim.x + threadIdx.x) >> 4;
  int l = threadIdx.x & 15;
  int g0 = threadIdx.x & 48;  // 16-lane group base within the wave
  if (n >= NN) return;        // exact division: never taken, no partial groups
  int l4 = l * 4;
  float4 xr4 = *(const float4*)&xr[n * DH + l4];
  float4 we4 = *(const float4*)&We[l4];
  float4 at4 = *(const float4*)&att[l4];
  int beg = rowptr[n], end = rowptr[n + 1];  // deg >= 1 (self loop)
  float M, D;
  float4 V;
  {  // peel first edge
    int2 c0 = csr[beg];
    float a = __int_as_float(c0.y);
    float4 sl = *(const float4*)&xl[c0.x * DH + l4];
    float v, p = 0.f;
    v = xr4.x + sl.x + a * we4.x; v = v > 0.f ? v : SLOPE * v; p += v * at4.x;
    v = xr4.y + sl.y + a * we4.y; v = v > 0.f ? v : SLOPE * v; p += v * at4.y;
    v = xr4.z + sl.z + a * we4.z; v = v > 0.f ? v : SLOPE * v; p += v * at4.z;
    v = xr4.w + sl.w + a * we4.w; v = v > 0.f ? v : SLOPE * v; p += v * at4.w;
    p += __shfl_xor(p, 1);
    p += __shfl_xor(p, 2);
    p += __shfl_xor(p, 4);
    p += __shfl_xor(p, 8);
    M = p; D = 1.f; V = sl;
  }
  for (int e0 = beg + 1; e0 < end; e0 += 16) {
    int2 cl = csr[min(e0 + l, end - 1)];  // coalesced 128B per group
    int cnt = min(16, end - e0);
    for (int i = 0; i < cnt; i += 4) {
      int mm = min(4, cnt - i);
      float4 sl[4];
      float av[4];
      #pragma unroll
      for (int j = 0; j < 4; j++) {
        if (j < mm) {
          int s = __shfl(cl.x, g0 + i + j);
          av[j] = __int_as_float(__shfl(cl.y, g0 + i + j));
          sl[j] = *(const float4*)&xl[s * DH + l4];  // 4 gathers in flight
        }
      }
      #pragma unroll
      for (int j = 0; j < 4; j++) {
        if (j < mm) {
          float a = av[j];
          float v, p = 0.f;
          v = xr4.x + sl[j].x + a * we4.x; v = v > 0.f ? v : SLOPE * v; p += v * at4.x;
          v = xr4.y + sl[j].y + a * we4.y; v = v > 0.f ? v : SLOPE * v; p += v * at4.y;
          v = xr4.z + sl[j].z + a * we4.z; v = v > 0.f ? v : SLOPE * v; p += v * at4.z;
          v = xr4.w + sl[j].w + a * we4.w; v = v > 0.f ? v : SLOPE * v; p += v * at4.w;
          p += __shfl_xor(p, 1);
          p += __shfl_xor(p, 2);
          p += __shfl_xor(p, 4);
          p += __shfl_xor(p, 8);
          float Mn = fmaxf(M, p);
          float sO = __expf(M - Mn), sN = __expf(p - Mn);
          D = D * sO + sN;
          V.x = fmaxf(V.x * sO, sl[j].x * sN);
          V.y = fmaxf(V.y * sO, sl[j].y * sN);
          V.z = fmaxf(V.z * sO, sl[j].z * sN);
          V.w = fmaxf(V.w * sO, sl[j].w * sN);
          M = Mn;
        }
      }
    }
  }
  float inv = 1.0f / D;
  float4 b = *(const float4*)&bias[l4];
  float4 o;
  o.x = fmaxf(V.x * inv + b.x, 0.f);
  o.y = fmaxf(V.y * inv + b.y, 0.f);
  o.z = fmaxf(V.z * inv + b.z, 0.f);
  o.w = fmaxf(V.w * inv + b.w, 0.f);
  if (!HEAD) {
    *(float4*)&h[n * DH + l4] = o;
  } else {
    // out[n] = relu(o @ W3 + b3) @ W4 + b4 ; lane l owns dims j = l4..l4+3
    float4 acc = {0.f, 0.f, 0.f, 0.f};
    #pragma unroll
    for (int kk = 0; kk < 16; kk++) {
      float4 hk;
      hk.x = __shfl(o.x, g0 + kk);
      hk.y = __shfl(o.y, g0 + kk);
      hk.z = __shfl(o.z, g0 + kk);
      hk.w = __shfl(o.w, g0 + kk);
      #pragma unroll
      for (int c = 0; c < 4; c++) {
        float4 w = *(const float4*)&W3[(kk * 4 + c) * DH + l4];
        float hv = (&hk.x)[c];
        acc.x = fmaf(hv, w.x, acc.x);
        acc.y = fmaf(hv, w.y, acc.y);
        acc.z = fmaf(hv, w.z, acc.z);
        acc.w = fmaf(hv, w.w, acc.w);
      }
    }
    float4 b3v = *(const float4*)&b3[l4];
    float4 w4v = *(const float4*)&W4[l4];
    float t, p = 0.f;
    t = acc.x + b3v.x; t = t > 0.f ? t : 0.f; p += t * w4v.x;
    t = acc.y + b3v.y; t = t > 0.f ? t : 0.f; p += t * w4v.y;
    t = acc.z + b3v.z; t = t > 0.f ? t : 0.f; p += t * w4v.z;
    t = acc.w + b3v.w; t = t > 0.f ? t : 0.f; p += t * w4v.w;
    p += __shfl_xor(p, 1);
    p += __shfl_xor(p, 2);
    p += __shfl_xor(p, 4);
    p += __shfl_xor(p, 8);
    if (l == 0) out[n] = p + b4[0];
  }
}

extern "C" void kernel_launch(void* const* d_in, const int* in_sizes, int n_in,
                              void* d_out, int out_size, void* d_ws, size_t ws_size,
                              hipStream_t stream) {
  const float* x      = (const float*)d_in[0];
  const int*   ei     = (const int*)d_in[1];
  const float* ea     = (const float*)d_in[2];
  const float* l1_Wl  = (const float*)d_in[3];
  const float* l1_bl  = (const float*)d_in[4];
  const float* l1_Wr  = (const float*)d_in[5];
  const float* l1_br  = (const float*)d_in[6];
  const float* l1_We  = (const float*)d_in[7];
  const float* l1_att = (const float*)d_in[8];
  const float* l1_bias= (const float*)d_in[9];
  const float* l2_Wl  = (const float*)d_in[10];
  const float* l2_bl  = (const float*)d_in[11];
  const float* l2_Wr  = (const float*)d_in[12];
  const float* l2_br  = (const float*)d_in[13];
  const float* l2_We  = (const float*)d_in[14];
  const float* l2_att = (const float*)d_in[15];
  const float* l2_bias= (const float*)d_in[16];
  const float* W3     = (const float*)d_in[17];
  const float* b3     = (const float*)d_in[18];
  const float* W4     = (const float*)d_in[19];
  const float* b4     = (const float*)d_in[20];
  float* out = (float*)d_out;

  float*    ws     = (float*)d_ws;
  float*    sum    = ws;                        // 256 floats (only [0] used)
  float*    xl     = ws + 256;                  // NN*DH
  float*    xr     = xl + NN * DH;              // NN*DH
  float*    h      = xr + NN * DH;              // NN*DH
  int2*     csr    = (int2*)(h + NN * DH);      // ETOT int2 (8B aligned)
  unsigned* rowptr = (unsigned*)(csr + ETOT);   // NN+1
  unsigned* wptr   = rowptr + NN + 1;           // NN
  unsigned* deg    = wptr + NN;                 // NN

  const int B = 256;
  const int gemm_blocks = (NN / 16 * 64 + B - 1) / B;  // 1563 (16 nodes/wave)
  const int edge_blocks = (ETOT + B - 1) / B;          // 6641
  const int attn_blocks = (NN * 16) / B;               // 6250

  // ---- graph preprocessing (once per call; shared by both layers) ----
  hipMemsetAsync(sum, 0, 256 * sizeof(float), stream);
  hipMemsetAsync(deg, 0, NN * sizeof(unsigned), stream);
  k_mean<<<256, B, 0, stream>>>(ea, sum);
  k_hist<<<edge_blocks, B, 0, stream>>>(ei, deg);
  k_scan<<<1, 1024, 0, stream>>>(deg, rowptr, wptr);
  k_scatter<<<edge_blocks, B, 0, stream>>>(ei, ea, sum, wptr, csr);

  // ---- layer 1 ----
  k_gemm2<DIN><<<gemm_blocks, B, 0, stream>>>(x, l1_Wl, l1_bl, l1_Wr, l1_br, xl, xr);
  k_attn<false><<<attn_blocks, B, 0, stream>>>(rowptr, csr, xl, xr, l1_We, l1_att,
                                               l1_bias, h, W3, b3, W4, b4, out);

  // ---- layer 2 + head (fused) ----
  k_gemm2<DH><<<gemm_blocks, B, 0, stream>>>(h, l2_Wl, l2_bl, l2_Wr, l2_br, xl, xr);
  k_attn<true><<<attn_blocks, B, 0, stream>>>(rowptr, csr, xl, xr, l2_We, l2_att,
                                              l2_bias, h, W3, b3, W4, b4, out);
}

// Round 2
// 955.826 us; speedup vs baseline: 3.3826x; 3.3826x over previous
//
#include <hip/hip_runtime.h>
#include <math.h>
#include <float.h>

#define NN 100000
#define NE 1600000
#define ETOT 1700000   // NE + NN self loops
#define DIN 264
#define DH 64
#define SLOPE 0.2f

__global__ void k_mean(const float* __restrict__ ea, float* __restrict__ sum) {
  float acc = 0.f;
  for (int i = blockIdx.x * blockDim.x + threadIdx.x; i < NE; i += gridDim.x * blockDim.x)
    acc += ea[i];
  #pragma unroll
  for (int off = 32; off > 0; off >>= 1) acc += __shfl_xor(acc, off);
  __shared__ float s[4];
  int lane = threadIdx.x & 63, w = threadIdx.x >> 6;
  if (lane == 0) s[w] = acc;
  __syncthreads();
  if (threadIdx.x == 0) atomicAdd(sum, s[0] + s[1] + s[2] + s[3]);
}

__global__ void k_hist(const int* __restrict__ ei, unsigned* __restrict__ deg) {
  int e = blockIdx.x * blockDim.x + threadIdx.x;
  if (e >= ETOT) return;
  int d = (e < NE) ? ei[NE + e] : e - NE;
  atomicAdd(&deg[d], 1u);
}

// single-block exclusive scan of deg -> rowptr (and wptr cursor copy)
__global__ void k_scan(const unsigned* __restrict__ deg, unsigned* __restrict__ rowptr,
                       unsigned* __restrict__ wptr) {
  __shared__ unsigned ls[1024];
  const int CH = (NN + 1023) / 1024;  // 98
  int t = threadIdx.x;
  int beg = t * CH, end = min(beg + CH, NN);
  unsigned s = 0;
  for (int i = beg; i < end; i++) s += deg[i];
  ls[t] = s;
  __syncthreads();
  for (int off = 1; off < 1024; off <<= 1) {
    unsigned v = (t >= off) ? ls[t - off] : 0u;
    __syncthreads();
    ls[t] += v;
    __syncthreads();
  }
  unsigned base = (t == 0) ? 0u : ls[t - 1];
  for (int i = beg; i < end; i++) {
    rowptr[i] = base;
    wptr[i] = base;
    base += deg[i];
  }
  if (t == 1023) rowptr[NN] = ls[1023];
}

__global__ void k_scatter(const int* __restrict__ ei, const float* __restrict__ ea,
                          const float* __restrict__ sump, unsigned* __restrict__ wptr,
                          int2* __restrict__ csr) {
  int e = blockIdx.x * blockDim.x + threadIdx.x;
  if (e >= ETOT) return;
  int s, d;
  float a;
  if (e < NE) {
    s = ei[e];
    d = ei[NE + e];
    a = ea[e];
  } else {
    s = d = e - NE;
    a = sump[0] * (1.0f / NE);
  }
  unsigned pos = atomicAdd(&wptr[d], 1u);
  csr[pos] = make_int2(s, __float_as_int(a));
}

// Block of 256 threads = 4 waves computes 32 nodes x 64 dims for TWO weight
// matrices (Wl, Wr).  X tile staged in LDS via a flat, perfectly-coalesced
// float4 copy (32 consecutive rows are contiguous in memory).  Each wave owns
// 8 rows; lane = output dim.  X values broadcast from LDS (wave-uniform
// ds_read_b128 -> HW broadcast, no bank conflict, no shfl).  W streams from
// L2 (135 KB resident).  Register budget ~45 VGPRs: fits the allocator's
// 64-VGPR / 8-waves-per-EU target WITHOUT scratch (rounds 0/1 spilled:
// WRITE_SIZE was 27x / 90x the real output; launch_bounds cannot raise the
// heuristic cap, so the fix is to fit under it and avoid (&v.x)[i] indexing).
template <int K>
__global__ __launch_bounds__(256)
void k_gemm2(const float* __restrict__ X,
             const float* __restrict__ Wl, const float* __restrict__ bl,
             const float* __restrict__ Wr, const float* __restrict__ br,
             float* __restrict__ xl, float* __restrict__ xr) {
  __shared__ float xs[32 * K];
  const int r0 = blockIdx.x * 32;  // NN % 32 == 0 -> 3125 blocks, exact
  {  // flat contiguous stage: 32*K floats, coalesced float4
    const float* src = X + (size_t)r0 * K;
    for (int i = threadIdx.x * 4; i < 32 * K; i += 256 * 4)
      *(float4*)&xs[i] = *(const float4*)&src[i];
  }
  __syncthreads();
  const int wave = threadIdx.x >> 6;
  const int lane = threadIdx.x & 63;
  const int m0 = wave * 8;  // first tile-row owned by this wave
  float accl[8], accr[8];
  #pragma unroll
  for (int m = 0; m < 8; m++) { accl[m] = 0.f; accr[m] = 0.f; }
  for (int kk = 0; kk < K; kk += 4) {  // K % 4 == 0 for 264 and 64
    float wl0 = Wl[(kk + 0) * DH + lane];
    float wl1 = Wl[(kk + 1) * DH + lane];
    float wl2 = Wl[(kk + 2) * DH + lane];
    float wl3 = Wl[(kk + 3) * DH + lane];
    float wr0 = Wr[(kk + 0) * DH + lane];
    float wr1 = Wr[(kk + 1) * DH + lane];
    float wr2 = Wr[(kk + 2) * DH + lane];
    float wr3 = Wr[(kk + 3) * DH + lane];
    #pragma unroll
    for (int m = 0; m < 8; m++) {
      float4 xv = *(const float4*)&xs[(m0 + m) * K + kk];  // uniform -> broadcast
      accl[m] = fmaf(xv.x, wl0, accl[m]);
      accl[m] = fmaf(xv.y, wl1, accl[m]);
      accl[m] = fmaf(xv.z, wl2, accl[m]);
      accl[m] = fmaf(xv.w, wl3, accl[m]);
      accr[m] = fmaf(xv.x, wr0, accr[m]);
      accr[m] = fmaf(xv.y, wr1, accr[m]);
      accr[m] = fmaf(xv.z, wr2, accr[m]);
      accr[m] = fmaf(xv.w, wr3, accr[m]);
    }
  }
  float blv = bl[lane], brv = br[lane];
  #pragma unroll
  for (int m = 0; m < 8; m++) {
    xl[(r0 + m0 + m) * DH + lane] = accl[m] + blv;
    xr[(r0 + m0 + m) * DH + lane] = accr[m] + brv;
  }
}

// Fused per-node attention: 16 lanes own one dst node; online softmax + max-aggregate.
// Edge loop: cooperative coalesced csr chunk loads + 4-edge gather batches.
// HEAD=true additionally computes out[n] = relu(h@W3+b3)@W4+b4 (no h write).
template <bool HEAD>
__global__ void k_attn(const unsigned* __restrict__ rowptr, const int2* __restrict__ csr,
                       const float* __restrict__ xl, const float* __restrict__ xr,
                       const float* __restrict__ We, const float* __restrict__ att,
                       const float* __restrict__ bias, float* __restrict__ h,
                       const float* __restrict__ W3, const float* __restrict__ b3,
                       const float* __restrict__ W4, const float* __restrict__ b4,
                       float* __restrict__ out) {
  int n = (blockIdx.x * blockDim.x + threadIdx.x) >> 4;
  int l = threadIdx.x & 15;
  int g0 = threadIdx.x & 48;  // 16-lane group base within the wave
  if (n >= NN) return;        // exact division: never taken, no partial groups
  int l4 = l * 4;
  float4 xr4 = *(const float4*)&xr[n * DH + l4];
  float4 we4 = *(const float4*)&We[l4];
  float4 at4 = *(const float4*)&att[l4];
  int beg = rowptr[n], end = rowptr[n + 1];  // deg >= 1 (self loop)
  float M, D;
  float4 V;
  {  // peel first edge
    int2 c0 = csr[beg];
    float a = __int_as_float(c0.y);
    float4 sl = *(const float4*)&xl[c0.x * DH + l4];
    float v, p = 0.f;
    v = xr4.x + sl.x + a * we4.x; v = v > 0.f ? v : SLOPE * v; p += v * at4.x;
    v = xr4.y + sl.y + a * we4.y; v = v > 0.f ? v : SLOPE * v; p += v * at4.y;
    v = xr4.z + sl.z + a * we4.z; v = v > 0.f ? v : SLOPE * v; p += v * at4.z;
    v = xr4.w + sl.w + a * we4.w; v = v > 0.f ? v : SLOPE * v; p += v * at4.w;
    p += __shfl_xor(p, 1);
    p += __shfl_xor(p, 2);
    p += __shfl_xor(p, 4);
    p += __shfl_xor(p, 8);
    M = p; D = 1.f; V = sl;
  }
  for (int e0 = beg + 1; e0 < end; e0 += 16) {
    int2 cl = csr[min(e0 + l, end - 1)];  // coalesced 128B per group
    int cnt = min(16, end - e0);
    for (int i = 0; i < cnt; i += 4) {
      int mm = min(4, cnt - i);
      float4 sl[4];
      float av[4];
      #pragma unroll
      for (int j = 0; j < 4; j++) {
        if (j < mm) {
          int s = __shfl(cl.x, g0 + i + j);
          av[j] = __int_as_float(__shfl(cl.y, g0 + i + j));
          sl[j] = *(const float4*)&xl[s * DH + l4];  // 4 gathers in flight
        }
      }
      #pragma unroll
      for (int j = 0; j < 4; j++) {
        if (j < mm) {
          float a = av[j];
          float v, p = 0.f;
          v = xr4.x + sl[j].x + a * we4.x; v = v > 0.f ? v : SLOPE * v; p += v * at4.x;
          v = xr4.y + sl[j].y + a * we4.y; v = v > 0.f ? v : SLOPE * v; p += v * at4.y;
          v = xr4.z + sl[j].z + a * we4.z; v = v > 0.f ? v : SLOPE * v; p += v * at4.z;
          v = xr4.w + sl[j].w + a * we4.w; v = v > 0.f ? v : SLOPE * v; p += v * at4.w;
          p += __shfl_xor(p, 1);
          p += __shfl_xor(p, 2);
          p += __shfl_xor(p, 4);
          p += __shfl_xor(p, 8);
          float Mn = fmaxf(M, p);
          float sO = __expf(M - Mn), sN = __expf(p - Mn);
          D = D * sO + sN;
          V.x = fmaxf(V.x * sO, sl[j].x * sN);
          V.y = fmaxf(V.y * sO, sl[j].y * sN);
          V.z = fmaxf(V.z * sO, sl[j].z * sN);
          V.w = fmaxf(V.w * sO, sl[j].w * sN);
          M = Mn;
        }
      }
    }
  }
  float inv = 1.0f / D;
  float4 b = *(const float4*)&bias[l4];
  float4 o;
  o.x = fmaxf(V.x * inv + b.x, 0.f);
  o.y = fmaxf(V.y * inv + b.y, 0.f);
  o.z = fmaxf(V.z * inv + b.z, 0.f);
  o.w = fmaxf(V.w * inv + b.w, 0.f);
  if (!HEAD) {
    *(float4*)&h[n * DH + l4] = o;
  } else {
    // out[n] = relu(o @ W3 + b3) @ W4 + b4 ; lane l owns dims j = l4..l4+3
    float4 acc = {0.f, 0.f, 0.f, 0.f};
    #pragma unroll
    for (int kk = 0; kk < 16; kk++) {
      float4 hk;
      hk.x = __shfl(o.x, g0 + kk);
      hk.y = __shfl(o.y, g0 + kk);
      hk.z = __shfl(o.z, g0 + kk);
      hk.w = __shfl(o.w, g0 + kk);
      float4 w0 = *(const float4*)&W3[(kk * 4 + 0) * DH + l4];
      acc.x = fmaf(hk.x, w0.x, acc.x);
      acc.y = fmaf(hk.x, w0.y, acc.y);
      acc.z = fmaf(hk.x, w0.z, acc.z);
      acc.w = fmaf(hk.x, w0.w, acc.w);
      float4 w1 = *(const float4*)&W3[(kk * 4 + 1) * DH + l4];
      acc.x = fmaf(hk.y, w1.x, acc.x);
      acc.y = fmaf(hk.y, w1.y, acc.y);
      acc.z = fmaf(hk.y, w1.z, acc.z);
      acc.w = fmaf(hk.y, w1.w, acc.w);
      float4 w2 = *(const float4*)&W3[(kk * 4 + 2) * DH + l4];
      acc.x = fmaf(hk.z, w2.x, acc.x);
      acc.y = fmaf(hk.z, w2.y, acc.y);
      acc.z = fmaf(hk.z, w2.z, acc.z);
      acc.w = fmaf(hk.z, w2.w, acc.w);
      float4 w3 = *(const float4*)&W3[(kk * 4 + 3) * DH + l4];
      acc.x = fmaf(hk.w, w3.x, acc.x);
      acc.y = fmaf(hk.w, w3.y, acc.y);
      acc.z = fmaf(hk.w, w3.z, acc.z);
      acc.w = fmaf(hk.w, w3.w, acc.w);
    }
    float4 b3v = *(const float4*)&b3[l4];
    float4 w4v = *(const float4*)&W4[l4];
    float t, p = 0.f;
    t = acc.x + b3v.x; t = t > 0.f ? t : 0.f; p += t * w4v.x;
    t = acc.y + b3v.y; t = t > 0.f ? t : 0.f; p += t * w4v.y;
    t = acc.z + b3v.z; t = t > 0.f ? t : 0.f; p += t * w4v.z;
    t = acc.w + b3v.w; t = t > 0.f ? t : 0.f; p += t * w4v.w;
    p += __shfl_xor(p, 1);
    p += __shfl_xor(p, 2);
    p += __shfl_xor(p, 4);
    p += __shfl_xor(p, 8);
    if (l == 0) out[n] = p + b4[0];
  }
}

extern "C" void kernel_launch(void* const* d_in, const int* in_sizes, int n_in,
                              void* d_out, int out_size, void* d_ws, size_t ws_size,
                              hipStream_t stream) {
  const float* x      = (const float*)d_in[0];
  const int*   ei     = (const int*)d_in[1];
  const float* ea     = (const float*)d_in[2];
  const float* l1_Wl  = (const float*)d_in[3];
  const float* l1_bl  = (const float*)d_in[4];
  const float* l1_Wr  = (const float*)d_in[5];
  const float* l1_br  = (const float*)d_in[6];
  const float* l1_We  = (const float*)d_in[7];
  const float* l1_att = (const float*)d_in[8];
  const float* l1_bias= (const float*)d_in[9];
  const float* l2_Wl  = (const float*)d_in[10];
  const float* l2_bl  = (const float*)d_in[11];
  const float* l2_Wr  = (const float*)d_in[12];
  const float* l2_br  = (const float*)d_in[13];
  const float* l2_We  = (const float*)d_in[14];
  const float* l2_att = (const float*)d_in[15];
  const float* l2_bias= (const float*)d_in[16];
  const float* W3     = (const float*)d_in[17];
  const float* b3     = (const float*)d_in[18];
  const float* W4     = (const float*)d_in[19];
  const float* b4     = (const float*)d_in[20];
  float* out = (float*)d_out;

  float*    ws     = (float*)d_ws;
  float*    sum    = ws;                        // 256 floats (only [0] used)
  float*    xl     = ws + 256;                  // NN*DH
  float*    xr     = xl + NN * DH;              // NN*DH
  float*    h      = xr + NN * DH;              // NN*DH
  int2*     csr    = (int2*)(h + NN * DH);      // ETOT int2 (8B aligned)
  unsigned* rowptr = (unsigned*)(csr + ETOT);   // NN+1
  unsigned* wptr   = rowptr + NN + 1;           // NN
  unsigned* deg    = wptr + NN;                 // NN

  const int B = 256;
  const int gemm_blocks = NN / 32;                  // 3125 (32 nodes/block)
  const int edge_blocks = (ETOT + B - 1) / B;       // 6641
  const int attn_blocks = (NN * 16) / B;            // 6250

  // ---- graph preprocessing (once per call; shared by both layers) ----
  hipMemsetAsync(sum, 0, 256 * sizeof(float), stream);
  hipMemsetAsync(deg, 0, NN * sizeof(unsigned), stream);
  k_mean<<<256, B, 0, stream>>>(ea, sum);
  k_hist<<<edge_blocks, B, 0, stream>>>(ei, deg);
  k_scan<<<1, 1024, 0, stream>>>(deg, rowptr, wptr);
  k_scatter<<<edge_blocks, B, 0, stream>>>(ei, ea, sum, wptr, csr);

  // ---- layer 1 ----
  k_gemm2<DIN><<<gemm_blocks, B, 0, stream>>>(x, l1_Wl, l1_bl, l1_Wr, l1_br, xl, xr);
  k_attn<false><<<attn_blocks, B, 0, stream>>>(rowptr, csr, xl, xr, l1_We, l1_att,
                                               l1_bias, h, W3, b3, W4, b4, out);

  // ---- layer 2 + head (fused) ----
  k_gemm2<DH><<<gemm_blocks, B, 0, stream>>>(h, l2_Wl, l2_bl, l2_Wr, l2_br, xl, xr);
  k_attn<true><<<attn_blocks, B, 0, stream>>>(rowptr, csr, xl, xr, l2_We, l2_att,
                                              l2_bias, h, W3, b3, W4, b4, out);
}

// Round 3
// 736.223 us; speedup vs baseline: 4.3915x; 1.2983x over previous
//
#include <hip/hip_runtime.h>
#include <math.h>
#include <float.h>

#define NN 100000
#define NE 1600000
#define ETOT 1700000   // NE + NN self loops
#define DIN 264
#define DH 64
#define SLOPE 0.2f
#define NB 98          // scan blocks: ceil(NN/1024)

__global__ void k_mean(const float* __restrict__ ea, float* __restrict__ sum) {
  float acc = 0.f;
  for (int i = blockIdx.x * blockDim.x + threadIdx.x; i < NE; i += gridDim.x * blockDim.x)
    acc += ea[i];
  #pragma unroll
  for (int off = 32; off > 0; off >>= 1) acc += __shfl_xor(acc, off);
  __shared__ float s[4];
  int lane = threadIdx.x & 63, w = threadIdx.x >> 6;
  if (lane == 0) s[w] = acc;
  __syncthreads();
  if (threadIdx.x == 0) atomicAdd(sum, s[0] + s[1] + s[2] + s[3]);
}

__global__ void k_hist(const int* __restrict__ ei, unsigned* __restrict__ deg) {
  int e = blockIdx.x * blockDim.x + threadIdx.x;
  if (e >= ETOT) return;
  int d = (e < NE) ? ei[NE + e] : e - NE;
  atomicAdd(&deg[d], 1u);
}

// ---- parallel 3-phase scan (replaces the 235us single-block k_scan:
//      OccupancyPercent was 0.15, one CU busy, 255 idle) ----

// phase 1: per-block (1024-element) sums
__global__ __launch_bounds__(256)
void k_bsum(const unsigned* __restrict__ deg, unsigned* __restrict__ bsum) {
  int i0 = blockIdx.x * 1024 + threadIdx.x * 4;
  unsigned s = 0;
  if (i0 + 3 < NN) {  // NN%4==0: uint4 is all-or-nothing
    uint4 v = *(const uint4*)&deg[i0];
    s = v.x + v.y + v.z + v.w;
  }
  #pragma unroll
  for (int off = 32; off > 0; off >>= 1) s += __shfl_xor(s, off);
  __shared__ unsigned ws[4];
  int lane = threadIdx.x & 63, w = threadIdx.x >> 6;
  if (lane == 0) ws[w] = s;
  __syncthreads();
  if (threadIdx.x == 0) bsum[blockIdx.x] = ws[0] + ws[1] + ws[2] + ws[3];
}

// phase 2: one tiny block exclusive-scans the NB block sums
__global__ __launch_bounds__(128)
void k_sscan(unsigned* __restrict__ bsum, unsigned* __restrict__ rowptr) {
  __shared__ unsigned ls[128];
  int t = threadIdx.x;
  unsigned v = (t < NB) ? bsum[t] : 0u;
  ls[t] = v;
  __syncthreads();
  for (int off = 1; off < 128; off <<= 1) {
    unsigned u = (t >= off) ? ls[t - off] : 0u;
    __syncthreads();
    ls[t] += u;
    __syncthreads();
  }
  if (t < NB) bsum[t] = ls[t] - v;  // exclusive
  if (t == 127) rowptr[NN] = ls[127];
}

// phase 3: per-block exclusive scan + block offset; coalesced uint4 writes
__global__ __launch_bounds__(256)
void k_scan2(const unsigned* __restrict__ deg, const unsigned* __restrict__ bsum,
             unsigned* __restrict__ rowptr, unsigned* __restrict__ wptr) {
  __shared__ unsigned ls[256];
  int i0 = blockIdx.x * 1024 + threadIdx.x * 4;
  unsigned d0 = 0, d1 = 0, d2 = 0, d3 = 0;
  if (i0 + 3 < NN) {
    uint4 v = *(const uint4*)&deg[i0];
    d0 = v.x; d1 = v.y; d2 = v.z; d3 = v.w;
  }
  unsigned ts = d0 + d1 + d2 + d3;
  ls[threadIdx.x] = ts;
  __syncthreads();
  for (int off = 1; off < 256; off <<= 1) {
    unsigned u = (threadIdx.x >= (unsigned)off) ? ls[threadIdx.x - off] : 0u;
    __syncthreads();
    ls[threadIdx.x] += u;
    __syncthreads();
  }
  unsigned base = bsum[blockIdx.x] + ls[threadIdx.x] - ts;  // exclusive
  if (i0 + 3 < NN) {
    uint4 r;
    r.x = base;
    r.y = base + d0;
    r.z = r.y + d1;
    r.w = r.z + d2;
    *(uint4*)&rowptr[i0] = r;
    *(uint4*)&wptr[i0] = r;
  }
}

__global__ void k_scatter(const int* __restrict__ ei, const float* __restrict__ ea,
                          const float* __restrict__ sump, unsigned* __restrict__ wptr,
                          int2* __restrict__ csr) {
  int e = blockIdx.x * blockDim.x + threadIdx.x;
  if (e >= ETOT) return;
  int s, d;
  float a;
  if (e < NE) {
    s = ei[e];
    d = ei[NE + e];
    a = ea[e];
  } else {
    s = d = e - NE;
    a = sump[0] * (1.0f / NE);
  }
  unsigned pos = atomicAdd(&wptr[d], 1u);
  csr[pos] = make_int2(s, __float_as_int(a));
}

// Block of 256 threads = 4 waves computes 32 nodes x 64 dims for TWO weight
// matrices (Wl, Wr).  X tile staged in LDS via a flat, perfectly-coalesced
// float4 copy.  Each wave owns 8 rows; lane = output dim.  X values broadcast
// from LDS (wave-uniform ds_read_b128).  W streams from L2.  ~45 VGPRs: fits
// the 64-VGPR/8-wave allocator target without scratch (rounds 0/1 spilled).
template <int K>
__global__ __launch_bounds__(256)
void k_gemm2(const float* __restrict__ X,
             const float* __restrict__ Wl, const float* __restrict__ bl,
             const float* __restrict__ Wr, const float* __restrict__ br,
             float* __restrict__ xl, float* __restrict__ xr) {
  __shared__ float xs[32 * K];
  const int r0 = blockIdx.x * 32;  // NN % 32 == 0 -> 3125 blocks, exact
  {  // flat contiguous stage: 32*K floats, coalesced float4
    const float* src = X + (size_t)r0 * K;
    for (int i = threadIdx.x * 4; i < 32 * K; i += 256 * 4)
      *(float4*)&xs[i] = *(const float4*)&src[i];
  }
  __syncthreads();
  const int wave = threadIdx.x >> 6;
  const int lane = threadIdx.x & 63;
  const int m0 = wave * 8;  // first tile-row owned by this wave
  float accl[8], accr[8];
  #pragma unroll
  for (int m = 0; m < 8; m++) { accl[m] = 0.f; accr[m] = 0.f; }
  for (int kk = 0; kk < K; kk += 4) {  // K % 4 == 0 for 264 and 64
    float wl0 = Wl[(kk + 0) * DH + lane];
    float wl1 = Wl[(kk + 1) * DH + lane];
    float wl2 = Wl[(kk + 2) * DH + lane];
    float wl3 = Wl[(kk + 3) * DH + lane];
    float wr0 = Wr[(kk + 0) * DH + lane];
    float wr1 = Wr[(kk + 1) * DH + lane];
    float wr2 = Wr[(kk + 2) * DH + lane];
    float wr3 = Wr[(kk + 3) * DH + lane];
    #pragma unroll
    for (int m = 0; m < 8; m++) {
      float4 xv = *(const float4*)&xs[(m0 + m) * K + kk];  // uniform -> broadcast
      accl[m] = fmaf(xv.x, wl0, accl[m]);
      accl[m] = fmaf(xv.y, wl1, accl[m]);
      accl[m] = fmaf(xv.z, wl2, accl[m]);
      accl[m] = fmaf(xv.w, wl3, accl[m]);
      accr[m] = fmaf(xv.x, wr0, accr[m]);
      accr[m] = fmaf(xv.y, wr1, accr[m]);
      accr[m] = fmaf(xv.z, wr2, accr[m]);
      accr[m] = fmaf(xv.w, wr3, accr[m]);
    }
  }
  float blv = bl[lane], brv = br[lane];
  #pragma unroll
  for (int m = 0; m < 8; m++) {
    xl[(r0 + m0 + m) * DH + lane] = accl[m] + blv;
    xr[(r0 + m0 + m) * DH + lane] = accr[m] + brv;
  }
}

// Fused per-node attention: 16 lanes own one dst node; online softmax + max-aggregate.
// Edge loop: cooperative coalesced csr chunk loads + 4-edge gather batches.
// HEAD=true additionally computes out[n] = relu(h@W3+b3)@W4+b4 (no h write).
template <bool HEAD>
__global__ void k_attn(const unsigned* __restrict__ rowptr, const int2* __restrict__ csr,
                       const float* __restrict__ xl, const float* __restrict__ xr,
                       const float* __restrict__ We, const float* __restrict__ att,
                       const float* __restrict__ bias, float* __restrict__ h,
                       const float* __restrict__ W3, const float* __restrict__ b3,
                       const float* __restrict__ W4, const float* __restrict__ b4,
                       float* __restrict__ out) {
  int n = (blockIdx.x * blockDim.x + threadIdx.x) >> 4;
  int l = threadIdx.x & 15;
  int g0 = threadIdx.x & 48;  // 16-lane group base within the wave
  if (n >= NN) return;        // exact division: never taken, no partial groups
  int l4 = l * 4;
  float4 xr4 = *(const float4*)&xr[n * DH + l4];
  float4 we4 = *(const float4*)&We[l4];
  float4 at4 = *(const float4*)&att[l4];
  int beg = rowptr[n], end = rowptr[n + 1];  // deg >= 1 (self loop)
  float M, D;
  float4 V;
  {  // peel first edge
    int2 c0 = csr[beg];
    float a = __int_as_float(c0.y);
    float4 sl = *(const float4*)&xl[c0.x * DH + l4];
    float v, p = 0.f;
    v = xr4.x + sl.x + a * we4.x; v = v > 0.f ? v : SLOPE * v; p += v * at4.x;
    v = xr4.y + sl.y + a * we4.y; v = v > 0.f ? v : SLOPE * v; p += v * at4.y;
    v = xr4.z + sl.z + a * we4.z; v = v > 0.f ? v : SLOPE * v; p += v * at4.z;
    v = xr4.w + sl.w + a * we4.w; v = v > 0.f ? v : SLOPE * v; p += v * at4.w;
    p += __shfl_xor(p, 1);
    p += __shfl_xor(p, 2);
    p += __shfl_xor(p, 4);
    p += __shfl_xor(p, 8);
    M = p; D = 1.f; V = sl;
  }
  for (int e0 = beg + 1; e0 < end; e0 += 16) {
    int2 cl = csr[min(e0 + l, end - 1)];  // coalesced 128B per group
    int cnt = min(16, end - e0);
    for (int i = 0; i < cnt; i += 4) {
      int mm = min(4, cnt - i);
      float4 sl[4];
      float av[4];
      #pragma unroll
      for (int j = 0; j < 4; j++) {
        if (j < mm) {
          int s = __shfl(cl.x, g0 + i + j);
          av[j] = __int_as_float(__shfl(cl.y, g0 + i + j));
          sl[j] = *(const float4*)&xl[s * DH + l4];  // 4 gathers in flight
        }
      }
      #pragma unroll
      for (int j = 0; j < 4; j++) {
        if (j < mm) {
          float a = av[j];
          float v, p = 0.f;
          v = xr4.x + sl[j].x + a * we4.x; v = v > 0.f ? v : SLOPE * v; p += v * at4.x;
          v = xr4.y + sl[j].y + a * we4.y; v = v > 0.f ? v : SLOPE * v; p += v * at4.y;
          v = xr4.z + sl[j].z + a * we4.z; v = v > 0.f ? v : SLOPE * v; p += v * at4.z;
          v = xr4.w + sl[j].w + a * we4.w; v = v > 0.f ? v : SLOPE * v; p += v * at4.w;
          p += __shfl_xor(p, 1);
          p += __shfl_xor(p, 2);
          p += __shfl_xor(p, 4);
          p += __shfl_xor(p, 8);
          float Mn = fmaxf(M, p);
          float sO = __expf(M - Mn), sN = __expf(p - Mn);
          D = D * sO + sN;
          V.x = fmaxf(V.x * sO, sl[j].x * sN);
          V.y = fmaxf(V.y * sO, sl[j].y * sN);
          V.z = fmaxf(V.z * sO, sl[j].z * sN);
          V.w = fmaxf(V.w * sO, sl[j].w * sN);
          M = Mn;
        }
      }
    }
  }
  float inv = 1.0f / D;
  float4 b = *(const float4*)&bias[l4];
  float4 o;
  o.x = fmaxf(V.x * inv + b.x, 0.f);
  o.y = fmaxf(V.y * inv + b.y, 0.f);
  o.z = fmaxf(V.z * inv + b.z, 0.f);
  o.w = fmaxf(V.w * inv + b.w, 0.f);
  if (!HEAD) {
    *(float4*)&h[n * DH + l4] = o;
  } else {
    // out[n] = relu(o @ W3 + b3) @ W4 + b4 ; lane l owns dims j = l4..l4+3
    float4 acc = {0.f, 0.f, 0.f, 0.f};
    #pragma unroll
    for (int kk = 0; kk < 16; kk++) {
      float4 hk;
      hk.x = __shfl(o.x, g0 + kk);
      hk.y = __shfl(o.y, g0 + kk);
      hk.z = __shfl(o.z, g0 + kk);
      hk.w = __shfl(o.w, g0 + kk);
      float4 w0 = *(const float4*)&W3[(kk * 4 + 0) * DH + l4];
      acc.x = fmaf(hk.x, w0.x, acc.x);
      acc.y = fmaf(hk.x, w0.y, acc.y);
      acc.z = fmaf(hk.x, w0.z, acc.z);
      acc.w = fmaf(hk.x, w0.w, acc.w);
      float4 w1 = *(const float4*)&W3[(kk * 4 + 1) * DH + l4];
      acc.x = fmaf(hk.y, w1.x, acc.x);
      acc.y = fmaf(hk.y, w1.y, acc.y);
      acc.z = fmaf(hk.y, w1.z, acc.z);
      acc.w = fmaf(hk.y, w1.w, acc.w);
      float4 w2 = *(const float4*)&W3[(kk * 4 + 2) * DH + l4];
      acc.x = fmaf(hk.z, w2.x, acc.x);
      acc.y = fmaf(hk.z, w2.y, acc.y);
      acc.z = fmaf(hk.z, w2.z, acc.z);
      acc.w = fmaf(hk.z, w2.w, acc.w);
      float4 w3 = *(const float4*)&W3[(kk * 4 + 3) * DH + l4];
      acc.x = fmaf(hk.w, w3.x, acc.x);
      acc.y = fmaf(hk.w, w3.y, acc.y);
      acc.z = fmaf(hk.w, w3.z, acc.z);
      acc.w = fmaf(hk.w, w3.w, acc.w);
    }
    float4 b3v = *(const float4*)&b3[l4];
    float4 w4v = *(const float4*)&W4[l4];
    float t, p = 0.f;
    t = acc.x + b3v.x; t = t > 0.f ? t : 0.f; p += t * w4v.x;
    t = acc.y + b3v.y; t = t > 0.f ? t : 0.f; p += t * w4v.y;
    t = acc.z + b3v.z; t = t > 0.f ? t : 0.f; p += t * w4v.z;
    t = acc.w + b3v.w; t = t > 0.f ? t : 0.f; p += t * w4v.w;
    p += __shfl_xor(p, 1);
    p += __shfl_xor(p, 2);
    p += __shfl_xor(p, 4);
    p += __shfl_xor(p, 8);
    if (l == 0) out[n] = p + b4[0];
  }
}

extern "C" void kernel_launch(void* const* d_in, const int* in_sizes, int n_in,
                              void* d_out, int out_size, void* d_ws, size_t ws_size,
                              hipStream_t stream) {
  const float* x      = (const float*)d_in[0];
  const int*   ei     = (const int*)d_in[1];
  const float* ea     = (const float*)d_in[2];
  const float* l1_Wl  = (const float*)d_in[3];
  const float* l1_bl  = (const float*)d_in[4];
  const float* l1_Wr  = (const float*)d_in[5];
  const float* l1_br  = (const float*)d_in[6];
  const float* l1_We  = (const float*)d_in[7];
  const float* l1_att = (const float*)d_in[8];
  const float* l1_bias= (const float*)d_in[9];
  const float* l2_Wl  = (const float*)d_in[10];
  const float* l2_bl  = (const float*)d_in[11];
  const float* l2_Wr  = (const float*)d_in[12];
  const float* l2_br  = (const float*)d_in[13];
  const float* l2_We  = (const float*)d_in[14];
  const float* l2_att = (const float*)d_in[15];
  const float* l2_bias= (const float*)d_in[16];
  const float* W3     = (const float*)d_in[17];
  const float* b3     = (const float*)d_in[18];
  const float* W4     = (const float*)d_in[19];
  const float* b4     = (const float*)d_in[20];
  float* out = (float*)d_out;

  float*    ws     = (float*)d_ws;
  float*    sum    = ws;                        // 256 floats (only [0] used)
  float*    xl     = ws + 256;                  // NN*DH
  float*    xr     = xl + NN * DH;              // NN*DH
  float*    h      = xr + NN * DH;              // NN*DH
  int2*     csr    = (int2*)(h + NN * DH);      // ETOT int2 (8B aligned)
  unsigned* rowptr = (unsigned*)(csr + ETOT);   // NN+1 (+3 pad for alignment)
  unsigned* wptr   = rowptr + NN + 4;           // NN   (16B aligned)
  unsigned* deg    = wptr + NN;                 // NN   (16B aligned)
  unsigned* bsum   = deg + NN;                  // NB   (16B aligned)

  const int B = 256;
  const int gemm_blocks = NN / 32;                  // 3125 (32 nodes/block)
  const int edge_blocks = (ETOT + B - 1) / B;       // 6641
  const int attn_blocks = (NN * 16) / B;            // 6250

  // ---- graph preprocessing (once per call; shared by both layers) ----
  hipMemsetAsync(sum, 0, 256 * sizeof(float), stream);
  hipMemsetAsync(deg, 0, NN * sizeof(unsigned), stream);
  k_mean<<<256, B, 0, stream>>>(ea, sum);
  k_hist<<<edge_blocks, B, 0, stream>>>(ei, deg);
  k_bsum<<<NB, B, 0, stream>>>(deg, bsum);
  k_sscan<<<1, 128, 0, stream>>>(bsum, rowptr);
  k_scan2<<<NB, B, 0, stream>>>(deg, bsum, rowptr, wptr);
  k_scatter<<<edge_blocks, B, 0, stream>>>(ei, ea, sum, wptr, csr);

  // ---- layer 1 ----
  k_gemm2<DIN><<<gemm_blocks, B, 0, stream>>>(x, l1_Wl, l1_bl, l1_Wr, l1_br, xl, xr);
  k_attn<false><<<attn_blocks, B, 0, stream>>>(rowptr, csr, xl, xr, l1_We, l1_att,
                                               l1_bias, h, W3, b3, W4, b4, out);

  // ---- layer 2 + head (fused) ----
  k_gemm2<DH><<<gemm_blocks, B, 0, stream>>>(h, l2_Wl, l2_bl, l2_Wr, l2_br, xl, xr);
  k_attn<true><<<attn_blocks, B, 0, stream>>>(rowptr, csr, xl, xr, l2_We, l2_att,
                                              l2_bias, h, W3, b3, W4, b4, out);
}

// Round 4
// 710.520 us; speedup vs baseline: 4.5504x; 1.0362x over previous
//
#include <hip/hip_runtime.h>
#include <math.h>
#include <float.h>

#define NN 100000
#define NE 1600000
#define ETOT 1700000   // NE + NN self loops
#define DIN 264
#define DH 64
#define SLOPE 0.2f
#define NB 98          // scan blocks: ceil(NN/1024)

typedef __attribute__((ext_vector_type(8))) short s8v;   // 8 bf16 = 4 VGPR
typedef __attribute__((ext_vector_type(4))) float f4v;   // MFMA acc

__device__ __forceinline__ unsigned short f2bf(float x) {  // rne f32->bf16
  unsigned u = __float_as_uint(x);
  u += 0x7FFFu + ((u >> 16) & 1u);
  return (unsigned short)(u >> 16);
}
__device__ __forceinline__ float bf2f(unsigned short h) {
  return __uint_as_float(((unsigned)h) << 16);
}

__global__ void k_mean(const float* __restrict__ ea, float* __restrict__ sum) {
  float acc = 0.f;
  for (int i = blockIdx.x * blockDim.x + threadIdx.x; i < NE; i += gridDim.x * blockDim.x)
    acc += ea[i];
  #pragma unroll
  for (int off = 32; off > 0; off >>= 1) acc += __shfl_xor(acc, off);
  __shared__ float s[4];
  int lane = threadIdx.x & 63, w = threadIdx.x >> 6;
  if (lane == 0) s[w] = acc;
  __syncthreads();
  if (threadIdx.x == 0) atomicAdd(sum, s[0] + s[1] + s[2] + s[3]);
}

__global__ void k_hist(const int* __restrict__ ei, unsigned* __restrict__ deg) {
  int e = blockIdx.x * blockDim.x + threadIdx.x;
  if (e >= ETOT) return;
  int d = (e < NE) ? ei[NE + e] : e - NE;
  atomicAdd(&deg[d], 1u);
}

// ---- parallel 3-phase scan ----
__global__ __launch_bounds__(256)
void k_bsum(const unsigned* __restrict__ deg, unsigned* __restrict__ bsum) {
  int i0 = blockIdx.x * 1024 + threadIdx.x * 4;
  unsigned s = 0;
  if (i0 + 3 < NN) {
    uint4 v = *(const uint4*)&deg[i0];
    s = v.x + v.y + v.z + v.w;
  }
  #pragma unroll
  for (int off = 32; off > 0; off >>= 1) s += __shfl_xor(s, off);
  __shared__ unsigned ws[4];
  int lane = threadIdx.x & 63, w = threadIdx.x >> 6;
  if (lane == 0) ws[w] = s;
  __syncthreads();
  if (threadIdx.x == 0) bsum[blockIdx.x] = ws[0] + ws[1] + ws[2] + ws[3];
}

__global__ __launch_bounds__(128)
void k_sscan(unsigned* __restrict__ bsum, unsigned* __restrict__ rowptr) {
  __shared__ unsigned ls[128];
  int t = threadIdx.x;
  unsigned v = (t < NB) ? bsum[t] : 0u;
  ls[t] = v;
  __syncthreads();
  for (int off = 1; off < 128; off <<= 1) {
    unsigned u = (t >= off) ? ls[t - off] : 0u;
    __syncthreads();
    ls[t] += u;
    __syncthreads();
  }
  if (t < NB) bsum[t] = ls[t] - v;  // exclusive
  if (t == 127) rowptr[NN] = ls[127];
}

__global__ __launch_bounds__(256)
void k_scan2(const unsigned* __restrict__ deg, const unsigned* __restrict__ bsum,
             unsigned* __restrict__ rowptr, unsigned* __restrict__ wptr) {
  __shared__ unsigned ls[256];
  int i0 = blockIdx.x * 1024 + threadIdx.x * 4;
  unsigned d0 = 0, d1 = 0, d2 = 0, d3 = 0;
  if (i0 + 3 < NN) {
    uint4 v = *(const uint4*)&deg[i0];
    d0 = v.x; d1 = v.y; d2 = v.z; d3 = v.w;
  }
  unsigned ts = d0 + d1 + d2 + d3;
  ls[threadIdx.x] = ts;
  __syncthreads();
  for (int off = 1; off < 256; off <<= 1) {
    unsigned u = (threadIdx.x >= (unsigned)off) ? ls[threadIdx.x - off] : 0u;
    __syncthreads();
    ls[threadIdx.x] += u;
    __syncthreads();
  }
  unsigned base = bsum[blockIdx.x] + ls[threadIdx.x] - ts;  // exclusive
  if (i0 + 3 < NN) {
    uint4 r;
    r.x = base;
    r.y = base + d0;
    r.z = r.y + d1;
    r.w = r.z + d2;
    *(uint4*)&rowptr[i0] = r;
    *(uint4*)&wptr[i0] = r;
  }
}

__global__ void k_scatter(const int* __restrict__ ei, const float* __restrict__ ea,
                          const float* __restrict__ sump, unsigned* __restrict__ wptr,
                          int2* __restrict__ csr) {
  int e = blockIdx.x * blockDim.x + threadIdx.x;
  if (e >= ETOT) return;
  int s, d;
  float a;
  if (e < NE) {
    s = ei[e];
    d = ei[NE + e];
    a = ea[e];
  } else {
    s = d = e - NE;
    a = sump[0] * (1.0f / NE);
  }
  unsigned pos = atomicAdd(&wptr[d], 1u);
  csr[pos] = make_int2(s, __float_as_int(a));
}

// Repack Wl|Wr (K x 64 row-major fp32) into MFMA B-fragment order, split
// bf16 hi/lo.  8 n-tiles total (0-3 -> Wl, 4-7 -> Wr); per fragment, lane l
// supplies B[k = kc*32 + 8*(l>>4) + i][n = nt*16 + (l&15)] (zero-pad k >= K).
// Fragment storage: wf[((ntg*KC + kc)*64 + lane)*8 + i] -> main-loop B-loads
// are lane-contiguous 16B (perfectly coalesced, L2-resident).
template <int K>
__global__ __launch_bounds__(256)
void k_wprep(const float* __restrict__ Wl, const float* __restrict__ Wr,
             unsigned short* __restrict__ wfh, unsigned short* __restrict__ wfl) {
  constexpr int KC = (K + 31) / 32;
  int t = blockIdx.x * blockDim.x + threadIdx.x;  // one thread per fragment-lane
  if (t >= 8 * KC * 64) return;
  int lane = t & 63;
  int kc = (t >> 6) % KC;
  int ntg = t / (64 * KC);
  const float* src = (ntg < 4) ? Wl : Wr;
  int n = (ntg & 3) * 16 + (lane & 15);
  int k0 = kc * 32 + (lane >> 4) * 8;
  #pragma unroll
  for (int i = 0; i < 8; i++) {
    int k = k0 + i;
    float v = (k < K) ? src[k * DH + n] : 0.f;
    unsigned short hh = f2bf(v);
    wfh[t * 8 + i] = hh;
    wfl[t * 8 + i] = f2bf(v - bf2f(hh));
  }
}

// MFMA GEMM: [xl xr] = X @ [Wl Wr] + [bl br] via split-bf16
// (Xh*Wh + Xh*Wlo + Xlo*Wh; dropped lo*lo term <= 2^-16 relative).
// Block = 64 rows x 128 cols, 4 waves; wave w owns n-tiles {2w, 2w+1}
// (w<2 -> xl, w>=2 -> xr) and all 4 m-tiles.  X staged in LDS as bf16 hi/lo
// planes, K zero-padded to 32-multiple, row stride +8 shorts -> ds_read_b128
// is 2-way bank-aliased (free, m136).  Per K-chunk/wave: 8 ds_read_b128 +
// 4 coalesced B-frag loads + 24 x mfma_f32_16x16x32_bf16.
// amdgpu_waves_per_eu(2): LDS limits to 2 blocks/CU anyway, so let the
// allocator use >64 VGPR instead of spilling (rounds 0/1 lesson).
template <int K>
__global__ __launch_bounds__(256) __attribute__((amdgpu_waves_per_eu(2)))
void k_mm(const float* __restrict__ X,
          const unsigned short* __restrict__ wfh, const unsigned short* __restrict__ wfl,
          const float* __restrict__ bl, const float* __restrict__ br,
          float* __restrict__ xl, float* __restrict__ xr) {
  constexpr int KC = (K + 31) / 32;
  constexpr int KP = KC * 32;
  constexpr int SP = KP + 8;  // +8 shorts: bank-spread for the A-frag reads
  __shared__ unsigned short lsh[64 * SP];
  __shared__ unsigned short lsl[64 * SP];
  const int r0 = blockIdx.x * 64;
  const int tid = threadIdx.x;
  if constexpr (KP > K) {  // zero the k-pad strip [K, KP)
    constexpr int PADW = (KP - K) / 2;  // uints per row
    for (int t = tid; t < 64 * PADW; t += 256) {
      int row = t / PADW, c = t - row * PADW;
      *(unsigned*)&lsh[row * SP + K + 2 * c] = 0u;
      *(unsigned*)&lsl[row * SP + K + 2 * c] = 0u;
    }
  }
  {  // stage X -> LDS bf16 hi/lo (coalesced float2 loads, packed uint writes)
    constexpr int HK = K / 2;
    for (int p = tid; p < 64 * HK; p += 256) {
      int row = p / HK, kp = p - row * HK;
      int grow = r0 + row;
      float a = 0.f, b = 0.f;
      if (grow < NN) {
        float2 v = *(const float2*)&X[(size_t)grow * K + 2 * kp];
        a = v.x; b = v.y;
      }
      unsigned short ha = f2bf(a), hb = f2bf(b);
      unsigned short la = f2bf(a - bf2f(ha)), lb = f2bf(b - bf2f(hb));
      *(unsigned*)&lsh[row * SP + 2 * kp] = (unsigned)ha | ((unsigned)hb << 16);
      *(unsigned*)&lsl[row * SP + 2 * kp] = (unsigned)la | ((unsigned)lb << 16);
    }
  }
  __syncthreads();
  const int lane = tid & 63, w = tid >> 6;
  const int kq = lane >> 4;   // k-octet / C-row group
  const int ar = lane & 15;   // A row within tile / C col
  f4v acc[4][2];
  #pragma unroll
  for (int mt = 0; mt < 4; mt++)
    #pragma unroll
    for (int j = 0; j < 2; j++)
      acc[mt][j] = (f4v){0.f, 0.f, 0.f, 0.f};
  for (int kc = 0; kc < KC; kc++) {
    const int kb = kc * 32 + kq * 8;
    s8v ah[4], al[4];
    #pragma unroll
    for (int mt = 0; mt < 4; mt++) {
      ah[mt] = *(const s8v*)&lsh[(mt * 16 + ar) * SP + kb];
      al[mt] = *(const s8v*)&lsl[(mt * 16 + ar) * SP + kb];
    }
    #pragma unroll
    for (int j = 0; j < 2; j++) {
      const int bidx = (((w * 2 + j) * KC + kc) * 64 + lane) * 8;
      s8v bh = *(const s8v*)&wfh[bidx];
      s8v bv = *(const s8v*)&wfl[bidx];
      #pragma unroll
      for (int mt = 0; mt < 4; mt++) {
        acc[mt][j] = __builtin_amdgcn_mfma_f32_16x16x32_bf16(ah[mt], bh, acc[mt][j], 0, 0, 0);
        acc[mt][j] = __builtin_amdgcn_mfma_f32_16x16x32_bf16(ah[mt], bv, acc[mt][j], 0, 0, 0);
        acc[mt][j] = __builtin_amdgcn_mfma_f32_16x16x32_bf16(al[mt], bh, acc[mt][j], 0, 0, 0);
      }
    }
  }
  // C/D layout (m89-verified): col = lane&15, row = (lane>>4)*4 + reg
  const int mat = w >> 1;
  const float* bias = mat ? br : bl;
  float* outp = mat ? xr : xl;
  #pragma unroll
  for (int j = 0; j < 2; j++) {
    int col = ((w & 1) * 2 + j) * 16 + ar;
    float bv = bias[col];
    #pragma unroll
    for (int mt = 0; mt < 4; mt++) {
      #pragma unroll
      for (int r = 0; r < 4; r++) {
        int grow = r0 + mt * 16 + kq * 4 + r;
        if (grow < NN) outp[(size_t)grow * DH + col] = acc[mt][j][r] + bv;
      }
    }
  }
}

// Fused per-node attention: 16 lanes own one dst node; online softmax + max-aggregate.
template <bool HEAD>
__global__ void k_attn(const unsigned* __restrict__ rowptr, const int2* __restrict__ csr,
                       const float* __restrict__ xl, const float* __restrict__ xr,
                       const float* __restrict__ We, const float* __restrict__ att,
                       const float* __restrict__ bias, float* __restrict__ h,
                       const float* __restrict__ W3, const float* __restrict__ b3,
                       const float* __restrict__ W4, const float* __restrict__ b4,
                       float* __restrict__ out) {
  int n = (blockIdx.x * blockDim.x + threadIdx.x) >> 4;
  int l = threadIdx.x & 15;
  int g0 = threadIdx.x & 48;  // 16-lane group base within the wave
  if (n >= NN) return;        // exact division: never taken, no partial groups
  int l4 = l * 4;
  float4 xr4 = *(const float4*)&xr[n * DH + l4];
  float4 we4 = *(const float4*)&We[l4];
  float4 at4 = *(const float4*)&att[l4];
  int beg = rowptr[n], end = rowptr[n + 1];  // deg >= 1 (self loop)
  float M, D;
  float4 V;
  {  // peel first edge
    int2 c0 = csr[beg];
    float a = __int_as_float(c0.y);
    float4 sl = *(const float4*)&xl[c0.x * DH + l4];
    float v, p = 0.f;
    v = xr4.x + sl.x + a * we4.x; v = v > 0.f ? v : SLOPE * v; p += v * at4.x;
    v = xr4.y + sl.y + a * we4.y; v = v > 0.f ? v : SLOPE * v; p += v * at4.y;
    v = xr4.z + sl.z + a * we4.z; v = v > 0.f ? v : SLOPE * v; p += v * at4.z;
    v = xr4.w + sl.w + a * we4.w; v = v > 0.f ? v : SLOPE * v; p += v * at4.w;
    p += __shfl_xor(p, 1);
    p += __shfl_xor(p, 2);
    p += __shfl_xor(p, 4);
    p += __shfl_xor(p, 8);
    M = p; D = 1.f; V = sl;
  }
  for (int e0 = beg + 1; e0 < end; e0 += 16) {
    int2 cl = csr[min(e0 + l, end - 1)];  // coalesced 128B per group
    int cnt = min(16, end - e0);
    for (int i = 0; i < cnt; i += 4) {
      int mm = min(4, cnt - i);
      float4 sl[4];
      float av[4];
      #pragma unroll
      for (int j = 0; j < 4; j++) {
        if (j < mm) {
          int s = __shfl(cl.x, g0 + i + j);
          av[j] = __int_as_float(__shfl(cl.y, g0 + i + j));
          sl[j] = *(const float4*)&xl[s * DH + l4];  // 4 gathers in flight
        }
      }
      #pragma unroll
      for (int j = 0; j < 4; j++) {
        if (j < mm) {
          float a = av[j];
          float v, p = 0.f;
          v = xr4.x + sl[j].x + a * we4.x; v = v > 0.f ? v : SLOPE * v; p += v * at4.x;
          v = xr4.y + sl[j].y + a * we4.y; v = v > 0.f ? v : SLOPE * v; p += v * at4.y;
          v = xr4.z + sl[j].z + a * we4.z; v = v > 0.f ? v : SLOPE * v; p += v * at4.z;
          v = xr4.w + sl[j].w + a * we4.w; v = v > 0.f ? v : SLOPE * v; p += v * at4.w;
          p += __shfl_xor(p, 1);
          p += __shfl_xor(p, 2);
          p += __shfl_xor(p, 4);
          p += __shfl_xor(p, 8);
          float Mn = fmaxf(M, p);
          float sO = __expf(M - Mn), sN = __expf(p - Mn);
          D = D * sO + sN;
          V.x = fmaxf(V.x * sO, sl[j].x * sN);
          V.y = fmaxf(V.y * sO, sl[j].y * sN);
          V.z = fmaxf(V.z * sO, sl[j].z * sN);
          V.w = fmaxf(V.w * sO, sl[j].w * sN);
          M = Mn;
        }
      }
    }
  }
  float inv = 1.0f / D;
  float4 b = *(const float4*)&bias[l4];
  float4 o;
  o.x = fmaxf(V.x * inv + b.x, 0.f);
  o.y = fmaxf(V.y * inv + b.y, 0.f);
  o.z = fmaxf(V.z * inv + b.z, 0.f);
  o.w = fmaxf(V.w * inv + b.w, 0.f);
  if (!HEAD) {
    *(float4*)&h[n * DH + l4] = o;
  } else {
    // out[n] = relu(o @ W3 + b3) @ W4 + b4 ; lane l owns dims j = l4..l4+3
    float4 acc = {0.f, 0.f, 0.f, 0.f};
    #pragma unroll
    for (int kk = 0; kk < 16; kk++) {
      float4 hk;
      hk.x = __shfl(o.x, g0 + kk);
      hk.y = __shfl(o.y, g0 + kk);
      hk.z = __shfl(o.z, g0 + kk);
      hk.w = __shfl(o.w, g0 + kk);
      float4 w0 = *(const float4*)&W3[(kk * 4 + 0) * DH + l4];
      acc.x = fmaf(hk.x, w0.x, acc.x);
      acc.y = fmaf(hk.x, w0.y, acc.y);
      acc.z = fmaf(hk.x, w0.z, acc.z);
      acc.w = fmaf(hk.x, w0.w, acc.w);
      float4 w1 = *(const float4*)&W3[(kk * 4 + 1) * DH + l4];
      acc.x = fmaf(hk.y, w1.x, acc.x);
      acc.y = fmaf(hk.y, w1.y, acc.y);
      acc.z = fmaf(hk.y, w1.z, acc.z);
      acc.w = fmaf(hk.y, w1.w, acc.w);
      float4 w2 = *(const float4*)&W3[(kk * 4 + 2) * DH + l4];
      acc.x = fmaf(hk.z, w2.x, acc.x);
      acc.y = fmaf(hk.z, w2.y, acc.y);
      acc.z = fmaf(hk.z, w2.z, acc.z);
      acc.w = fmaf(hk.z, w2.w, acc.w);
      float4 w3 = *(const float4*)&W3[(kk * 4 + 3) * DH + l4];
      acc.x = fmaf(hk.w, w3.x, acc.x);
      acc.y = fmaf(hk.w, w3.y, acc.y);
      acc.z = fmaf(hk.w, w3.z, acc.z);
      acc.w = fmaf(hk.w, w3.w, acc.w);
    }
    float4 b3v = *(const float4*)&b3[l4];
    float4 w4v = *(const float4*)&W4[l4];
    float t, p = 0.f;
    t = acc.x + b3v.x; t = t > 0.f ? t : 0.f; p += t * w4v.x;
    t = acc.y + b3v.y; t = t > 0.f ? t : 0.f; p += t * w4v.y;
    t = acc.z + b3v.z; t = t > 0.f ? t : 0.f; p += t * w4v.z;
    t = acc.w + b3v.w; t = t > 0.f ? t : 0.f; p += t * w4v.w;
    p += __shfl_xor(p, 1);
    p += __shfl_xor(p, 2);
    p += __shfl_xor(p, 4);
    p += __shfl_xor(p, 8);
    if (l == 0) out[n] = p + b4[0];
  }
}

extern "C" void kernel_launch(void* const* d_in, const int* in_sizes, int n_in,
                              void* d_out, int out_size, void* d_ws, size_t ws_size,
                              hipStream_t stream) {
  const float* x      = (const float*)d_in[0];
  const int*   ei     = (const int*)d_in[1];
  const float* ea     = (const float*)d_in[2];
  const float* l1_Wl  = (const float*)d_in[3];
  const float* l1_bl  = (const float*)d_in[4];
  const float* l1_Wr  = (const float*)d_in[5];
  const float* l1_br  = (const float*)d_in[6];
  const float* l1_We  = (const float*)d_in[7];
  const float* l1_att = (const float*)d_in[8];
  const float* l1_bias= (const float*)d_in[9];
  const float* l2_Wl  = (const float*)d_in[10];
  const float* l2_bl  = (const float*)d_in[11];
  const float* l2_Wr  = (const float*)d_in[12];
  const float* l2_br  = (const float*)d_in[13];
  const float* l2_We  = (const float*)d_in[14];
  const float* l2_att = (const float*)d_in[15];
  const float* l2_bias= (const float*)d_in[16];
  const float* W3     = (const float*)d_in[17];
  const float* b3     = (const float*)d_in[18];
  const float* W4     = (const float*)d_in[19];
  const float* b4     = (const float*)d_in[20];
  float* out = (float*)d_out;

  float*    ws     = (float*)d_ws;
  float*    sum    = ws;                        // 256 floats (only [0] used)
  float*    xl     = ws + 256;                  // NN*DH
  float*    xr     = xl + NN * DH;              // NN*DH
  float*    h      = xr + NN * DH;              // NN*DH
  int2*     csr    = (int2*)(h + NN * DH);      // ETOT int2 (8B aligned)
  unsigned* rowptr = (unsigned*)(csr + ETOT);   // NN+1 (+3 pad for alignment)
  unsigned* wptr   = rowptr + NN + 4;           // NN   (16B aligned)
  unsigned* deg    = wptr + NN;                 // NN   (16B aligned)
  unsigned* bsum   = deg + NN;                  // NB, padded to 128 uints
  unsigned short* wf1h = (unsigned short*)(bsum + 128);  // 8*9*64*8 = 36864
  unsigned short* wf1l = wf1h + 36864;
  unsigned short* wf2h = wf1l + 36864;          // 8*2*64*8 = 8192
  unsigned short* wf2l = wf2h + 8192;

  const int B = 256;
  const int mm_blocks   = (NN + 63) / 64;           // 1563 (64 rows/block)
  const int edge_blocks = (ETOT + B - 1) / B;       // 6641
  const int attn_blocks = (NN * 16) / B;            // 6250

  // ---- graph preprocessing + weight repack (independent of each other) ----
  hipMemsetAsync(sum, 0, 256 * sizeof(float), stream);
  hipMemsetAsync(deg, 0, NN * sizeof(unsigned), stream);
  k_wprep<DIN><<<(8 * 9 * 64 + B - 1) / B, B, 0, stream>>>(l1_Wl, l1_Wr, wf1h, wf1l);
  k_wprep<DH><<<(8 * 2 * 64 + B - 1) / B, B, 0, stream>>>(l2_Wl, l2_Wr, wf2h, wf2l);
  k_mean<<<256, B, 0, stream>>>(ea, sum);
  k_hist<<<edge_blocks, B, 0, stream>>>(ei, deg);
  k_bsum<<<NB, B, 0, stream>>>(deg, bsum);
  k_sscan<<<1, 128, 0, stream>>>(bsum, rowptr);
  k_scan2<<<NB, B, 0, stream>>>(deg, bsum, rowptr, wptr);
  k_scatter<<<edge_blocks, B, 0, stream>>>(ei, ea, sum, wptr, csr);

  // ---- layer 1 ----
  k_mm<DIN><<<mm_blocks, B, 0, stream>>>(x, wf1h, wf1l, l1_bl, l1_br, xl, xr);
  k_attn<false><<<attn_blocks, B, 0, stream>>>(rowptr, csr, xl, xr, l1_We, l1_att,
                                               l1_bias, h, W3, b3, W4, b4, out);

  // ---- layer 2 + head (fused) ----
  k_mm<DH><<<mm_blocks, B, 0, stream>>>(h, wf2h, wf2l, l2_bl, l2_br, xl, xr);
  k_attn<true><<<attn_blocks, B, 0, stream>>>(rowptr, csr, xl, xr, l2_We, l2_att,
                                              l2_bias, h, W3, b3, W4, b4, out);
}

// Round 5
// 661.902 us; speedup vs baseline: 4.8846x; 1.0735x over previous
//
#include <hip/hip_runtime.h>
#include <math.h>
#include <float.h>

#define NN 100000
#define NE 1600000
#define ETOT 1700000   // NE + NN self loops
#define DIN 264
#define DH 64
#define SLOPE 0.2f
#define NB 98          // scan blocks: ceil(NN/1024)

typedef __attribute__((ext_vector_type(8))) short s8v;   // 8 bf16 = 4 VGPR
typedef __attribute__((ext_vector_type(4))) float f4v;   // MFMA acc

__device__ __forceinline__ unsigned short f2bf(float x) {  // rne f32->bf16
  unsigned u = __float_as_uint(x);
  u += 0x7FFFu + ((u >> 16) & 1u);
  return (unsigned short)(u >> 16);
}
__device__ __forceinline__ float bf2f(unsigned short h) {
  return __uint_as_float(((unsigned)h) << 16);
}

__global__ void k_mean(const float* __restrict__ ea, float* __restrict__ sum) {
  float acc = 0.f;
  for (int i = blockIdx.x * blockDim.x + threadIdx.x; i < NE; i += gridDim.x * blockDim.x)
    acc += ea[i];
  #pragma unroll
  for (int off = 32; off > 0; off >>= 1) acc += __shfl_xor(acc, off);
  __shared__ float s[4];
  int lane = threadIdx.x & 63, w = threadIdx.x >> 6;
  if (lane == 0) s[w] = acc;
  __syncthreads();
  if (threadIdx.x == 0) atomicAdd(sum, s[0] + s[1] + s[2] + s[3]);
}

__global__ void k_hist(const int* __restrict__ ei, unsigned* __restrict__ deg) {
  int e = blockIdx.x * blockDim.x + threadIdx.x;
  if (e >= ETOT) return;
  int d = (e < NE) ? ei[NE + e] : e - NE;
  atomicAdd(&deg[d], 1u);
}

// ---- parallel 3-phase scan ----
__global__ __launch_bounds__(256)
void k_bsum(const unsigned* __restrict__ deg, unsigned* __restrict__ bsum) {
  int i0 = blockIdx.x * 1024 + threadIdx.x * 4;
  unsigned s = 0;
  if (i0 + 3 < NN) {
    uint4 v = *(const uint4*)&deg[i0];
    s = v.x + v.y + v.z + v.w;
  }
  #pragma unroll
  for (int off = 32; off > 0; off >>= 1) s += __shfl_xor(s, off);
  __shared__ unsigned ws[4];
  int lane = threadIdx.x & 63, w = threadIdx.x >> 6;
  if (lane == 0) ws[w] = s;
  __syncthreads();
  if (threadIdx.x == 0) bsum[blockIdx.x] = ws[0] + ws[1] + ws[2] + ws[3];
}

__global__ __launch_bounds__(128)
void k_sscan(unsigned* __restrict__ bsum, unsigned* __restrict__ rowptr) {
  __shared__ unsigned ls[128];
  int t = threadIdx.x;
  unsigned v = (t < NB) ? bsum[t] : 0u;
  ls[t] = v;
  __syncthreads();
  for (int off = 1; off < 128; off <<= 1) {
    unsigned u = (t >= off) ? ls[t - off] : 0u;
    __syncthreads();
    ls[t] += u;
    __syncthreads();
  }
  if (t < NB) bsum[t] = ls[t] - v;  // exclusive
  if (t == 127) rowptr[NN] = ls[127];
}

__global__ __launch_bounds__(256)
void k_scan2(const unsigned* __restrict__ deg, const unsigned* __restrict__ bsum,
             unsigned* __restrict__ rowptr, unsigned* __restrict__ wptr) {
  __shared__ unsigned ls[256];
  int i0 = blockIdx.x * 1024 + threadIdx.x * 4;
  unsigned d0 = 0, d1 = 0, d2 = 0, d3 = 0;
  if (i0 + 3 < NN) {
    uint4 v = *(const uint4*)&deg[i0];
    d0 = v.x; d1 = v.y; d2 = v.z; d3 = v.w;
  }
  unsigned ts = d0 + d1 + d2 + d3;
  ls[threadIdx.x] = ts;
  __syncthreads();
  for (int off = 1; off < 256; off <<= 1) {
    unsigned u = (threadIdx.x >= (unsigned)off) ? ls[threadIdx.x - off] : 0u;
    __syncthreads();
    ls[threadIdx.x] += u;
    __syncthreads();
  }
  unsigned base = bsum[blockIdx.x] + ls[threadIdx.x] - ts;  // exclusive
  if (i0 + 3 < NN) {
    uint4 r;
    r.x = base;
    r.y = base + d0;
    r.z = r.y + d1;
    r.w = r.z + d2;
    *(uint4*)&rowptr[i0] = r;
    *(uint4*)&wptr[i0] = r;
  }
}

__global__ void k_scatter(const int* __restrict__ ei, const float* __restrict__ ea,
                          const float* __restrict__ sump, unsigned* __restrict__ wptr,
                          int2* __restrict__ csr) {
  int e = blockIdx.x * blockDim.x + threadIdx.x;
  if (e >= ETOT) return;
  int s, d;
  float a;
  if (e < NE) {
    s = ei[e];
    d = ei[NE + e];
    a = ea[e];
  } else {
    s = d = e - NE;
    a = sump[0] * (1.0f / NE);
  }
  unsigned pos = atomicAdd(&wptr[d], 1u);
  csr[pos] = make_int2(s, __float_as_int(a));
}

// Repack Wl|Wr (K x 64 row-major fp32) into MFMA B-fragment order, split
// bf16 hi/lo.  8 n-tiles total (0-3 -> Wl, 4-7 -> Wr); per fragment, lane l
// supplies B[k = kc*32 + 8*(l>>4) + i][n = nt*16 + (l&15)] (zero-pad k >= K).
// Fragment storage: wf[((ntg*KC + kc)*64 + lane)*8 + i] -> B-loads are
// lane-contiguous 16B (perfectly coalesced, L2-resident).
template <int K>
__global__ __launch_bounds__(256)
void k_wprep(const float* __restrict__ Wl, const float* __restrict__ Wr,
             unsigned short* __restrict__ wfh, unsigned short* __restrict__ wfl) {
  constexpr int KC = (K + 31) / 32;
  int t = blockIdx.x * blockDim.x + threadIdx.x;  // one thread per fragment-lane
  if (t >= 8 * KC * 64) return;
  int lane = t & 63;
  int kc = (t >> 6) % KC;
  int ntg = t / (64 * KC);
  const float* src = (ntg < 4) ? Wl : Wr;
  int n = (ntg & 3) * 16 + (lane & 15);
  int k0 = kc * 32 + (lane >> 4) * 8;
  #pragma unroll
  for (int i = 0; i < 8; i++) {
    int k = k0 + i;
    float v = (k < K) ? src[k * DH + n] : 0.f;
    unsigned short hh = f2bf(v);
    wfh[t * 8 + i] = hh;
    wfl[t * 8 + i] = f2bf(v - bf2f(hh));
  }
}

// MFMA GEMM: [xl xr] = X @ [Wl Wr] + [bl br] via split-bf16
// (Xh*Wh + Xh*Wlo + Xlo*Wh; dropped lo*lo term <= 2^-16 relative).
//
// Round-4 lesson: 4 global B-loads INSIDE each kc iteration + 2 waves/SIMD
// = latency-bound (MfmaUtil 6%, all pipes idle).  Round-5 structure:
//   - 512 threads = 8 waves per 64-row block; wave w owns ONE n-tile
//     (w<4 -> xl cols, w>=4 -> xr cols), all 4 m-tiles.
//   - Wave's ENTIRE B set preloaded to registers (KC*2 s8v = 72 VGPR @K=264)
//     BEFORE staging -> load latency hides under X->LDS conversion.
//   - K-loop: 8 ds_read_b128 + 12 MFMA per kc, ZERO global ops.
//   - amdgpu_waves_per_eu(4): 128-VGPR budget; LDS 75776B -> 2 blocks/CU
//     -> 16 waves/CU (4/SIMD), 2x round 4.
template <int K>
__global__ __launch_bounds__(512) __attribute__((amdgpu_waves_per_eu(4)))
void k_mm(const float* __restrict__ X,
          const unsigned short* __restrict__ wfh, const unsigned short* __restrict__ wfl,
          const float* __restrict__ bl, const float* __restrict__ br,
          float* __restrict__ xl, float* __restrict__ xr) {
  constexpr int KC = (K + 31) / 32;
  constexpr int KP = KC * 32;
  constexpr int SP = KP + 8;  // +8 shorts: bank-spread for the A-frag reads
  __shared__ unsigned short lsh[64 * SP];
  __shared__ unsigned short lsl[64 * SP];
  const int r0 = blockIdx.x * 64;
  const int tid = threadIdx.x;
  const int lane = tid & 63, w = tid >> 6;
  const int kq = lane >> 4;   // k-octet / C-row group
  const int ar = lane & 15;   // A row within tile / C col

  // ---- preload this wave's B fragments (n-tile = w) for all kc ----
  s8v bh[KC], bv[KC];
  #pragma unroll
  for (int kc = 0; kc < KC; kc++) {
    const int bidx = ((w * KC + kc) * 64 + lane) * 8;
    bh[kc] = *(const s8v*)&wfh[bidx];
    bv[kc] = *(const s8v*)&wfl[bidx];
  }

  // ---- stage X -> LDS bf16 hi/lo (coalesced float2 loads) ----
  if constexpr (KP > K) {  // zero the k-pad strip [K, KP)
    constexpr int PADW = (KP - K) / 2;  // uints per row
    for (int t = tid; t < 64 * PADW; t += 512) {
      int row = t / PADW, c = t - row * PADW;
      *(unsigned*)&lsh[row * SP + K + 2 * c] = 0u;
      *(unsigned*)&lsl[row * SP + K + 2 * c] = 0u;
    }
  }
  {
    constexpr int HK = K / 2;
    for (int p = tid; p < 64 * HK; p += 512) {
      int row = p / HK, kp = p - row * HK;
      int grow = r0 + row;
      float a = 0.f, b = 0.f;
      if (grow < NN) {
        float2 v = *(const float2*)&X[(size_t)grow * K + 2 * kp];
        a = v.x; b = v.y;
      }
      unsigned short ha = f2bf(a), hb = f2bf(b);
      unsigned short la = f2bf(a - bf2f(ha)), lb = f2bf(b - bf2f(hb));
      *(unsigned*)&lsh[row * SP + 2 * kp] = (unsigned)ha | ((unsigned)hb << 16);
      *(unsigned*)&lsl[row * SP + 2 * kp] = (unsigned)la | ((unsigned)lb << 16);
    }
  }
  __syncthreads();

  // ---- K-loop: LDS reads + MFMA only ----
  f4v acc[4];
  #pragma unroll
  for (int mt = 0; mt < 4; mt++) acc[mt] = (f4v){0.f, 0.f, 0.f, 0.f};
  #pragma unroll
  for (int kc = 0; kc < KC; kc++) {
    const int kb = kc * 32 + kq * 8;
    #pragma unroll
    for (int mt = 0; mt < 4; mt++) {
      s8v ah = *(const s8v*)&lsh[(mt * 16 + ar) * SP + kb];
      s8v al = *(const s8v*)&lsl[(mt * 16 + ar) * SP + kb];
      acc[mt] = __builtin_amdgcn_mfma_f32_16x16x32_bf16(ah, bh[kc], acc[mt], 0, 0, 0);
      acc[mt] = __builtin_amdgcn_mfma_f32_16x16x32_bf16(ah, bv[kc], acc[mt], 0, 0, 0);
      acc[mt] = __builtin_amdgcn_mfma_f32_16x16x32_bf16(al, bh[kc], acc[mt], 0, 0, 0);
    }
  }

  // C/D layout (m89-verified): col = lane&15, row = (lane>>4)*4 + reg
  const float* bias = (w < 4) ? bl : br;
  float* outp = (w < 4) ? xl : xr;
  const int col = (w & 3) * 16 + ar;
  const float bvv = bias[col];
  #pragma unroll
  for (int mt = 0; mt < 4; mt++) {
    #pragma unroll
    for (int r = 0; r < 4; r++) {
      int grow = r0 + mt * 16 + kq * 4 + r;
      if (grow < NN) outp[(size_t)grow * DH + col] = acc[mt][r] + bvv;
    }
  }
}

// Fused per-node attention: 16 lanes own one dst node; online softmax + max-aggregate.
template <bool HEAD>
__global__ void k_attn(const unsigned* __restrict__ rowptr, const int2* __restrict__ csr,
                       const float* __restrict__ xl, const float* __restrict__ xr,
                       const float* __restrict__ We, const float* __restrict__ att,
                       const float* __restrict__ bias, float* __restrict__ h,
                       const float* __restrict__ W3, const float* __restrict__ b3,
                       const float* __restrict__ W4, const float* __restrict__ b4,
                       float* __restrict__ out) {
  int n = (blockIdx.x * blockDim.x + threadIdx.x) >> 4;
  int l = threadIdx.x & 15;
  int g0 = threadIdx.x & 48;  // 16-lane group base within the wave
  if (n >= NN) return;        // exact division: never taken, no partial groups
  int l4 = l * 4;
  float4 xr4 = *(const float4*)&xr[n * DH + l4];
  float4 we4 = *(const float4*)&We[l4];
  float4 at4 = *(const float4*)&att[l4];
  int beg = rowptr[n], end = rowptr[n + 1];  // deg >= 1 (self loop)
  float M, D;
  float4 V;
  {  // peel first edge
    int2 c0 = csr[beg];
    float a = __int_as_float(c0.y);
    float4 sl = *(const float4*)&xl[c0.x * DH + l4];
    float v, p = 0.f;
    v = xr4.x + sl.x + a * we4.x; v = v > 0.f ? v : SLOPE * v; p += v * at4.x;
    v = xr4.y + sl.y + a * we4.y; v = v > 0.f ? v : SLOPE * v; p += v * at4.y;
    v = xr4.z + sl.z + a * we4.z; v = v > 0.f ? v : SLOPE * v; p += v * at4.z;
    v = xr4.w + sl.w + a * we4.w; v = v > 0.f ? v : SLOPE * v; p += v * at4.w;
    p += __shfl_xor(p, 1);
    p += __shfl_xor(p, 2);
    p += __shfl_xor(p, 4);
    p += __shfl_xor(p, 8);
    M = p; D = 1.f; V = sl;
  }
  for (int e0 = beg + 1; e0 < end; e0 += 16) {
    int2 cl = csr[min(e0 + l, end - 1)];  // coalesced 128B per group
    int cnt = min(16, end - e0);
    for (int i = 0; i < cnt; i += 4) {
      int mm = min(4, cnt - i);
      float4 sl[4];
      float av[4];
      #pragma unroll
      for (int j = 0; j < 4; j++) {
        if (j < mm) {
          int s = __shfl(cl.x, g0 + i + j);
          av[j] = __int_as_float(__shfl(cl.y, g0 + i + j));
          sl[j] = *(const float4*)&xl[s * DH + l4];  // 4 gathers in flight
        }
      }
      #pragma unroll
      for (int j = 0; j < 4; j++) {
        if (j < mm) {
          float a = av[j];
          float v, p = 0.f;
          v = xr4.x + sl[j].x + a * we4.x; v = v > 0.f ? v : SLOPE * v; p += v * at4.x;
          v = xr4.y + sl[j].y + a * we4.y; v = v > 0.f ? v : SLOPE * v; p += v * at4.y;
          v = xr4.z + sl[j].z + a * we4.z; v = v > 0.f ? v : SLOPE * v; p += v * at4.z;
          v = xr4.w + sl[j].w + a * we4.w; v = v > 0.f ? v : SLOPE * v; p += v * at4.w;
          p += __shfl_xor(p, 1);
          p += __shfl_xor(p, 2);
          p += __shfl_xor(p, 4);
          p += __shfl_xor(p, 8);
          float Mn = fmaxf(M, p);
          float sO = __expf(M - Mn), sN = __expf(p - Mn);
          D = D * sO + sN;
          V.x = fmaxf(V.x * sO, sl[j].x * sN);
          V.y = fmaxf(V.y * sO, sl[j].y * sN);
          V.z = fmaxf(V.z * sO, sl[j].z * sN);
          V.w = fmaxf(V.w * sO, sl[j].w * sN);
          M = Mn;
        }
      }
    }
  }
  float inv = 1.0f / D;
  float4 b = *(const float4*)&bias[l4];
  float4 o;
  o.x = fmaxf(V.x * inv + b.x, 0.f);
  o.y = fmaxf(V.y * inv + b.y, 0.f);
  o.z = fmaxf(V.z * inv + b.z, 0.f);
  o.w = fmaxf(V.w * inv + b.w, 0.f);
  if (!HEAD) {
    *(float4*)&h[n * DH + l4] = o;
  } else {
    // out[n] = relu(o @ W3 + b3) @ W4 + b4 ; lane l owns dims j = l4..l4+3
    float4 acc = {0.f, 0.f, 0.f, 0.f};
    #pragma unroll
    for (int kk = 0; kk < 16; kk++) {
      float4 hk;
      hk.x = __shfl(o.x, g0 + kk);
      hk.y = __shfl(o.y, g0 + kk);
      hk.z = __shfl(o.z, g0 + kk);
      hk.w = __shfl(o.w, g0 + kk);
      float4 w0 = *(const float4*)&W3[(kk * 4 + 0) * DH + l4];
      acc.x = fmaf(hk.x, w0.x, acc.x);
      acc.y = fmaf(hk.x, w0.y, acc.y);
      acc.z = fmaf(hk.x, w0.z, acc.z);
      acc.w = fmaf(hk.x, w0.w, acc.w);
      float4 w1 = *(const float4*)&W3[(kk * 4 + 1) * DH + l4];
      acc.x = fmaf(hk.y, w1.x, acc.x);
      acc.y = fmaf(hk.y, w1.y, acc.y);
      acc.z = fmaf(hk.y, w1.z, acc.z);
      acc.w = fmaf(hk.y, w1.w, acc.w);
      float4 w2 = *(const float4*)&W3[(kk * 4 + 2) * DH + l4];
      acc.x = fmaf(hk.z, w2.x, acc.x);
      acc.y = fmaf(hk.z, w2.y, acc.y);
      acc.z = fmaf(hk.z, w2.z, acc.z);
      acc.w = fmaf(hk.z, w2.w, acc.w);
      float4 w3 = *(const float4*)&W3[(kk * 4 + 3) * DH + l4];
      acc.x = fmaf(hk.w, w3.x, acc.x);
      acc.y = fmaf(hk.w, w3.y, acc.y);
      acc.z = fmaf(hk.w, w3.z, acc.z);
      acc.w = fmaf(hk.w, w3.w, acc.w);
    }
    float4 b3v = *(const float4*)&b3[l4];
    float4 w4v = *(const float4*)&W4[l4];
    float t, p = 0.f;
    t = acc.x + b3v.x; t = t > 0.f ? t : 0.f; p += t * w4v.x;
    t = acc.y + b3v.y; t = t > 0.f ? t : 0.f; p += t * w4v.y;
    t = acc.z + b3v.z; t = t > 0.f ? t : 0.f; p += t * w4v.z;
    t = acc.w + b3v.w; t = t > 0.f ? t : 0.f; p += t * w4v.w;
    p += __shfl_xor(p, 1);
    p += __shfl_xor(p, 2);
    p += __shfl_xor(p, 4);
    p += __shfl_xor(p, 8);
    if (l == 0) out[n] = p + b4[0];
  }
}

extern "C" void kernel_launch(void* const* d_in, const int* in_sizes, int n_in,
                              void* d_out, int out_size, void* d_ws, size_t ws_size,
                              hipStream_t stream) {
  const float* x      = (const float*)d_in[0];
  const int*   ei     = (const int*)d_in[1];
  const float* ea     = (const float*)d_in[2];
  const float* l1_Wl  = (const float*)d_in[3];
  const float* l1_bl  = (const float*)d_in[4];
  const float* l1_Wr  = (const float*)d_in[5];
  const float* l1_br  = (const float*)d_in[6];
  const float* l1_We  = (const float*)d_in[7];
  const float* l1_att = (const float*)d_in[8];
  const float* l1_bias= (const float*)d_in[9];
  const float* l2_Wl  = (const float*)d_in[10];
  const float* l2_bl  = (const float*)d_in[11];
  const float* l2_Wr  = (const float*)d_in[12];
  const float* l2_br  = (const float*)d_in[13];
  const float* l2_We  = (const float*)d_in[14];
  const float* l2_att = (const float*)d_in[15];
  const float* l2_bias= (const float*)d_in[16];
  const float* W3     = (const float*)d_in[17];
  const float* b3     = (const float*)d_in[18];
  const float* W4     = (const float*)d_in[19];
  const float* b4     = (const float*)d_in[20];
  float* out = (float*)d_out;

  float*    ws     = (float*)d_ws;
  float*    sum    = ws;                        // 256 floats (only [0] used)
  float*    xl     = ws + 256;                  // NN*DH
  float*    xr     = xl + NN * DH;              // NN*DH
  float*    h      = xr + NN * DH;              // NN*DH
  int2*     csr    = (int2*)(h + NN * DH);      // ETOT int2 (8B aligned)
  unsigned* rowptr = (unsigned*)(csr + ETOT);   // NN+1 (+3 pad for alignment)
  unsigned* wptr   = rowptr + NN + 4;           // NN   (16B aligned)
  unsigned* deg    = wptr + NN;                 // NN   (16B aligned)
  unsigned* bsum   = deg + NN;                  // NB, padded to 128 uints
  unsigned short* wf1h = (unsigned short*)(bsum + 128);  // 8*9*64*8 = 36864
  unsigned short* wf1l = wf1h + 36864;
  unsigned short* wf2h = wf1l + 36864;          // 8*2*64*8 = 8192
  unsigned short* wf2l = wf2h + 8192;

  const int B = 256;
  const int mm_blocks   = (NN + 63) / 64;           // 1563 (64 rows/block)
  const int edge_blocks = (ETOT + B - 1) / B;       // 6641
  const int attn_blocks = (NN * 16) / B;            // 6250

  // ---- graph preprocessing + weight repack (independent of each other) ----
  hipMemsetAsync(sum, 0, 256 * sizeof(float), stream);
  hipMemsetAsync(deg, 0, NN * sizeof(unsigned), stream);
  k_wprep<DIN><<<(8 * 9 * 64 + B - 1) / B, B, 0, stream>>>(l1_Wl, l1_Wr, wf1h, wf1l);
  k_wprep<DH><<<(8 * 2 * 64 + B - 1) / B, B, 0, stream>>>(l2_Wl, l2_Wr, wf2h, wf2l);
  k_mean<<<256, B, 0, stream>>>(ea, sum);
  k_hist<<<edge_blocks, B, 0, stream>>>(ei, deg);
  k_bsum<<<NB, B, 0, stream>>>(deg, bsum);
  k_sscan<<<1, 128, 0, stream>>>(bsum, rowptr);
  k_scan2<<<NB, B, 0, stream>>>(deg, bsum, rowptr, wptr);
  k_scatter<<<edge_blocks, B, 0, stream>>>(ei, ea, sum, wptr, csr);

  // ---- layer 1 ----
  k_mm<DIN><<<mm_blocks, 512, 0, stream>>>(x, wf1h, wf1l, l1_bl, l1_br, xl, xr);
  k_attn<false><<<attn_blocks, B, 0, stream>>>(rowptr, csr, xl, xr, l1_We, l1_att,
                                               l1_bias, h, W3, b3, W4, b4, out);

  // ---- layer 2 + head (fused) ----
  k_mm<DH><<<mm_blocks, 512, 0, stream>>>(h, wf2h, wf2l, l2_bl, l2_br, xl, xr);
  k_attn<true><<<attn_blocks, B, 0, stream>>>(rowptr, csr, xl, xr, l2_We, l2_att,
                                              l2_bias, h, W3, b3, W4, b4, out);
}

// Round 6
// 617.723 us; speedup vs baseline: 5.2340x; 1.0715x over previous
//
#include <hip/hip_runtime.h>
#include <math.h>
#include <float.h>

#define NN 100000
#define NE 1600000
#define ETOT 1700000   // NE + NN self loops
#define DIN 264
#define DH 64
#define SLOPE 0.2f
#define NB 98          // scan blocks: ceil(NN/1024)
#define NSHARD 8       // one dst-range shard per XCD
#define SHW 12500      // NN / NSHARD
#define EPB 2048       // edges per block-chunk in sharded edge kernels

typedef __attribute__((ext_vector_type(8))) short s8v;   // 8 bf16 = 4 VGPR
typedef __attribute__((ext_vector_type(4))) float f4v;   // MFMA acc

__device__ __forceinline__ unsigned short f2bf(float x) {  // rne f32->bf16
  unsigned u = __float_as_uint(x);
  u += 0x7FFFu + ((u >> 16) & 1u);
  return (unsigned short)(u >> 16);
}
__device__ __forceinline__ float bf2f(unsigned short h) {
  return __uint_as_float(((unsigned)h) << 16);
}

__global__ void k_mean(const float* __restrict__ ea, float* __restrict__ sum) {
  float acc = 0.f;
  for (int i = blockIdx.x * blockDim.x + threadIdx.x; i < NE; i += gridDim.x * blockDim.x)
    acc += ea[i];
  #pragma unroll
  for (int off = 32; off > 0; off >>= 1) acc += __shfl_xor(acc, off);
  __shared__ float s[4];
  int lane = threadIdx.x & 63, w = threadIdx.x >> 6;
  if (lane == 0) s[w] = acc;
  __syncthreads();
  if (threadIdx.x == 0) atomicAdd(sum, s[0] + s[1] + s[2] + s[3]);
}

// XCD-sharded histogram: blocks with blockIdx%8==b own dst range
// [b*SHW,(b+1)*SHW).  Round-robin block->XCD dispatch (perf heuristic,
// correctness shard-exhaustive) keeps each deg/csr line dirty on ONE XCD:
// round-5 counters showed 103MB HBM writes for 13.6MB of csr = one partial
// dirty-line writeback per 8B record, from cross-XCD line sharing.
__global__ __launch_bounds__(256)
void k_hist(const int* __restrict__ ei, unsigned* __restrict__ deg) {
  const int shard = blockIdx.x & (NSHARD - 1);
  const int g = blockIdx.x >> 3;
  const int dlo = shard * SHW, dhi = dlo + SHW;
  int e0 = g * EPB + threadIdx.x;
  #pragma unroll
  for (int k = 0; k < EPB / 256; k++) {
    int e = e0 + k * 256;
    if (e < ETOT) {
      int d = (e < NE) ? ei[NE + e] : e - NE;
      if (d >= dlo && d < dhi) atomicAdd(&deg[d], 1u);
    }
  }
}

// ---- parallel 3-phase scan ----
__global__ __launch_bounds__(256)
void k_bsum(const unsigned* __restrict__ deg, unsigned* __restrict__ bsum) {
  int i0 = blockIdx.x * 1024 + threadIdx.x * 4;
  unsigned s = 0;
  if (i0 + 3 < NN) {
    uint4 v = *(const uint4*)&deg[i0];
    s = v.x + v.y + v.z + v.w;
  }
  #pragma unroll
  for (int off = 32; off > 0; off >>= 1) s += __shfl_xor(s, off);
  __shared__ unsigned ws[4];
  int lane = threadIdx.x & 63, w = threadIdx.x >> 6;
  if (lane == 0) ws[w] = s;
  __syncthreads();
  if (threadIdx.x == 0) bsum[blockIdx.x] = ws[0] + ws[1] + ws[2] + ws[3];
}

__global__ __launch_bounds__(128)
void k_sscan(unsigned* __restrict__ bsum, unsigned* __restrict__ rowptr) {
  __shared__ unsigned ls[128];
  int t = threadIdx.x;
  unsigned v = (t < NB) ? bsum[t] : 0u;
  ls[t] = v;
  __syncthreads();
  for (int off = 1; off < 128; off <<= 1) {
    unsigned u = (t >= off) ? ls[t - off] : 0u;
    __syncthreads();
    ls[t] += u;
    __syncthreads();
  }
  if (t < NB) bsum[t] = ls[t] - v;  // exclusive
  if (t == 127) rowptr[NN] = ls[127];
}

__global__ __launch_bounds__(256)
void k_scan2(const unsigned* __restrict__ deg, const unsigned* __restrict__ bsum,
             unsigned* __restrict__ rowptr, unsigned* __restrict__ wptr) {
  __shared__ unsigned ls[256];
  int i0 = blockIdx.x * 1024 + threadIdx.x * 4;
  unsigned d0 = 0, d1 = 0, d2 = 0, d3 = 0;
  if (i0 + 3 < NN) {
    uint4 v = *(const uint4*)&deg[i0];
    d0 = v.x; d1 = v.y; d2 = v.z; d3 = v.w;
  }
  unsigned ts = d0 + d1 + d2 + d3;
  ls[threadIdx.x] = ts;
  __syncthreads();
  for (int off = 1; off < 256; off <<= 1) {
    unsigned u = (threadIdx.x >= (unsigned)off) ? ls[threadIdx.x - off] : 0u;
    __syncthreads();
    ls[threadIdx.x] += u;
    __syncthreads();
  }
  unsigned base = bsum[blockIdx.x] + ls[threadIdx.x] - ts;  // exclusive
  if (i0 + 3 < NN) {
    uint4 r;
    r.x = base;
    r.y = base + d0;
    r.z = r.y + d1;
    r.w = r.z + d2;
    *(uint4*)&rowptr[i0] = r;
    *(uint4*)&wptr[i0] = r;
  }
}

// XCD-sharded CSR scatter (see k_hist comment).  Each shard's csr window is
// ~1.7MB (< 4MB per-XCD L2): lines collect all their records on one XCD
// before writeback -> WRITE_SIZE should drop ~103MB -> ~real size.
__global__ __launch_bounds__(256)
void k_scatter(const int* __restrict__ ei, const float* __restrict__ ea,
               const float* __restrict__ sump, unsigned* __restrict__ wptr,
               int2* __restrict__ csr) {
  const int shard = blockIdx.x & (NSHARD - 1);
  const int g = blockIdx.x >> 3;
  const int dlo = shard * SHW, dhi = dlo + SHW;
  int e0 = g * EPB + threadIdx.x;
  #pragma unroll
  for (int k = 0; k < EPB / 256; k++) {
    int e = e0 + k * 256;
    if (e >= ETOT) continue;
    int d = (e < NE) ? ei[NE + e] : e - NE;
    if (d < dlo || d >= dhi) continue;
    int s;
    float a;
    if (e < NE) {
      s = ei[e];
      a = ea[e];
    } else {
      s = d;
      a = sump[0] * (1.0f / NE);
    }
    unsigned pos = atomicAdd(&wptr[d], 1u);
    csr[pos] = make_int2(s, __float_as_int(a));
  }
}

// Repack Wl|Wr (K x 64 row-major fp32) into MFMA B-fragment order, split
// bf16 hi/lo.  8 n-tiles total (0-3 -> Wl, 4-7 -> Wr); per fragment, lane l
// supplies B[k = kc*32 + 8*(l>>4) + i][n = nt*16 + (l&15)] (zero-pad k >= K).
template <int K>
__global__ __launch_bounds__(256)
void k_wprep(const float* __restrict__ Wl, const float* __restrict__ Wr,
             unsigned short* __restrict__ wfh, unsigned short* __restrict__ wfl) {
  constexpr int KC = (K + 31) / 32;
  int t = blockIdx.x * blockDim.x + threadIdx.x;  // one thread per fragment-lane
  if (t >= 8 * KC * 64) return;
  int lane = t & 63;
  int kc = (t >> 6) % KC;
  int ntg = t / (64 * KC);
  const float* src = (ntg < 4) ? Wl : Wr;
  int n = (ntg & 3) * 16 + (lane & 15);
  int k0 = kc * 32 + (lane >> 4) * 8;
  #pragma unroll
  for (int i = 0; i < 8; i++) {
    int k = k0 + i;
    float v = (k < K) ? src[k * DH + n] : 0.f;
    unsigned short hh = f2bf(v);
    wfh[t * 8 + i] = hh;
    wfl[t * 8 + i] = f2bf(v - bf2f(hh));
  }
}

// MFMA GEMM: [xl xr] = X @ [Wl Wr] + [bl br] via split-bf16
// (Xh*Wh + Xh*Wlo + Xlo*Wh; dropped lo*lo term <= 2^-16 relative).
// 512 threads = 8 waves per 64-row block; wave w owns ONE n-tile
// (w<4 -> xl cols, w>=4 -> xr cols), all 4 m-tiles.  Wave's ENTIRE B set
// preloaded to registers before staging; K-loop is LDS+MFMA only.
template <int K>
__global__ __launch_bounds__(512) __attribute__((amdgpu_waves_per_eu(4)))
void k_mm(const float* __restrict__ X,
          const unsigned short* __restrict__ wfh, const unsigned short* __restrict__ wfl,
          const float* __restrict__ bl, const float* __restrict__ br,
          float* __restrict__ xl, float* __restrict__ xr) {
  constexpr int KC = (K + 31) / 32;
  constexpr int KP = KC * 32;
  constexpr int SP = KP + 8;  // +8 shorts: bank-spread for the A-frag reads
  __shared__ unsigned short lsh[64 * SP];
  __shared__ unsigned short lsl[64 * SP];
  const int r0 = blockIdx.x * 64;
  const int tid = threadIdx.x;
  const int lane = tid & 63, w = tid >> 6;
  const int kq = lane >> 4;   // k-octet / C-row group
  const int ar = lane & 15;   // A row within tile / C col

  // ---- preload this wave's B fragments (n-tile = w) for all kc ----
  s8v bh[KC], bv[KC];
  #pragma unroll
  for (int kc = 0; kc < KC; kc++) {
    const int bidx = ((w * KC + kc) * 64 + lane) * 8;
    bh[kc] = *(const s8v*)&wfh[bidx];
    bv[kc] = *(const s8v*)&wfl[bidx];
  }

  // ---- stage X -> LDS bf16 hi/lo (coalesced float2 loads) ----
  if constexpr (KP > K) {  // zero the k-pad strip [K, KP)
    constexpr int PADW = (KP - K) / 2;  // uints per row
    for (int t = tid; t < 64 * PADW; t += 512) {
      int row = t / PADW, c = t - row * PADW;
      *(unsigned*)&lsh[row * SP + K + 2 * c] = 0u;
      *(unsigned*)&lsl[row * SP + K + 2 * c] = 0u;
    }
  }
  {
    constexpr int HK = K / 2;
    for (int p = tid; p < 64 * HK; p += 512) {
      int row = p / HK, kp = p - row * HK;
      int grow = r0 + row;
      float a = 0.f, b = 0.f;
      if (grow < NN) {
        float2 v = *(const float2*)&X[(size_t)grow * K + 2 * kp];
        a = v.x; b = v.y;
      }
      unsigned short ha = f2bf(a), hb = f2bf(b);
      unsigned short la = f2bf(a - bf2f(ha)), lb = f2bf(b - bf2f(hb));
      *(unsigned*)&lsh[row * SP + 2 * kp] = (unsigned)ha | ((unsigned)hb << 16);
      *(unsigned*)&lsl[row * SP + 2 * kp] = (unsigned)la | ((unsigned)lb << 16);
    }
  }
  __syncthreads();

  // ---- K-loop: LDS reads + MFMA only ----
  f4v acc[4];
  #pragma unroll
  for (int mt = 0; mt < 4; mt++) acc[mt] = (f4v){0.f, 0.f, 0.f, 0.f};
  #pragma unroll
  for (int kc = 0; kc < KC; kc++) {
    const int kb = kc * 32 + kq * 8;
    #pragma unroll
    for (int mt = 0; mt < 4; mt++) {
      s8v ah = *(const s8v*)&lsh[(mt * 16 + ar) * SP + kb];
      s8v al = *(const s8v*)&lsl[(mt * 16 + ar) * SP + kb];
      acc[mt] = __builtin_amdgcn_mfma_f32_16x16x32_bf16(ah, bh[kc], acc[mt], 0, 0, 0);
      acc[mt] = __builtin_amdgcn_mfma_f32_16x16x32_bf16(ah, bv[kc], acc[mt], 0, 0, 0);
      acc[mt] = __builtin_amdgcn_mfma_f32_16x16x32_bf16(al, bh[kc], acc[mt], 0, 0, 0);
    }
  }

  // C/D layout (m89-verified): col = lane&15, row = (lane>>4)*4 + reg
  const float* bias = (w < 4) ? bl : br;
  float* outp = (w < 4) ? xl : xr;
  const int col = (w & 3) * 16 + ar;
  const float bvv = bias[col];
  #pragma unroll
  for (int mt = 0; mt < 4; mt++) {
    #pragma unroll
    for (int r = 0; r < 4; r++) {
      int grow = r0 + mt * 16 + kq * 4 + r;
      if (grow < NN) outp[(size_t)grow * DH + col] = acc[mt][r] + bvv;
    }
  }
}

// Fused per-node attention: 16 lanes own one dst node; online softmax + max-aggregate.
template <bool HEAD>
__global__ void k_attn(const unsigned* __restrict__ rowptr, const int2* __restrict__ csr,
                       const float* __restrict__ xl, const float* __restrict__ xr,
                       const float* __restrict__ We, const float* __restrict__ att,
                       const float* __restrict__ bias, float* __restrict__ h,
                       const float* __restrict__ W3, const float* __restrict__ b3,
                       const float* __restrict__ W4, const float* __restrict__ b4,
                       float* __restrict__ out) {
  int n = (blockIdx.x * blockDim.x + threadIdx.x) >> 4;
  int l = threadIdx.x & 15;
  int g0 = threadIdx.x & 48;  // 16-lane group base within the wave
  if (n >= NN) return;        // exact division: never taken, no partial groups
  int l4 = l * 4;
  float4 xr4 = *(const float4*)&xr[n * DH + l4];
  float4 we4 = *(const float4*)&We[l4];
  float4 at4 = *(const float4*)&att[l4];
  int beg = rowptr[n], end = rowptr[n + 1];  // deg >= 1 (self loop)
  float M, D;
  float4 V;
  {  // peel first edge
    int2 c0 = csr[beg];
    float a = __int_as_float(c0.y);
    float4 sl = *(const float4*)&xl[c0.x * DH + l4];
    float v, p = 0.f;
    v = xr4.x + sl.x + a * we4.x; v = v > 0.f ? v : SLOPE * v; p += v * at4.x;
    v = xr4.y + sl.y + a * we4.y; v = v > 0.f ? v : SLOPE * v; p += v * at4.y;
    v = xr4.z + sl.z + a * we4.z; v = v > 0.f ? v : SLOPE * v; p += v * at4.z;
    v = xr4.w + sl.w + a * we4.w; v = v > 0.f ? v : SLOPE * v; p += v * at4.w;
    p += __shfl_xor(p, 1);
    p += __shfl_xor(p, 2);
    p += __shfl_xor(p, 4);
    p += __shfl_xor(p, 8);
    M = p; D = 1.f; V = sl;
  }
  for (int e0 = beg + 1; e0 < end; e0 += 16) {
    int2 cl = csr[min(e0 + l, end - 1)];  // coalesced 128B per group
    int cnt = min(16, end - e0);
    for (int i = 0; i < cnt; i += 4) {
      int mm = min(4, cnt - i);
      float4 sl[4];
      float av[4];
      #pragma unroll
      for (int j = 0; j < 4; j++) {
        if (j < mm) {
          int s = __shfl(cl.x, g0 + i + j);
          av[j] = __int_as_float(__shfl(cl.y, g0 + i + j));
          sl[j] = *(const float4*)&xl[s * DH + l4];  // 4 gathers in flight
        }
      }
      #pragma unroll
      for (int j = 0; j < 4; j++) {
        if (j < mm) {
          float a = av[j];
          float v, p = 0.f;
          v = xr4.x + sl[j].x + a * we4.x; v = v > 0.f ? v : SLOPE * v; p += v * at4.x;
          v = xr4.y + sl[j].y + a * we4.y; v = v > 0.f ? v : SLOPE * v; p += v * at4.y;
          v = xr4.z + sl[j].z + a * we4.z; v = v > 0.f ? v : SLOPE * v; p += v * at4.z;
          v = xr4.w + sl[j].w + a * we4.w; v = v > 0.f ? v : SLOPE * v; p += v * at4.w;
          p += __shfl_xor(p, 1);
          p += __shfl_xor(p, 2);
          p += __shfl_xor(p, 4);
          p += __shfl_xor(p, 8);
          float Mn = fmaxf(M, p);
          float sO = __expf(M - Mn), sN = __expf(p - Mn);
          D = D * sO + sN;
          V.x = fmaxf(V.x * sO, sl[j].x * sN);
          V.y = fmaxf(V.y * sO, sl[j].y * sN);
          V.z = fmaxf(V.z * sO, sl[j].z * sN);
          V.w = fmaxf(V.w * sO, sl[j].w * sN);
          M = Mn;
        }
      }
    }
  }
  float inv = 1.0f / D;
  float4 b = *(const float4*)&bias[l4];
  float4 o;
  o.x = fmaxf(V.x * inv + b.x, 0.f);
  o.y = fmaxf(V.y * inv + b.y, 0.f);
  o.z = fmaxf(V.z * inv + b.z, 0.f);
  o.w = fmaxf(V.w * inv + b.w, 0.f);
  if (!HEAD) {
    *(float4*)&h[n * DH + l4] = o;
  } else {
    // out[n] = relu(o @ W3 + b3) @ W4 + b4 ; lane l owns dims j = l4..l4+3
    float4 acc = {0.f, 0.f, 0.f, 0.f};
    #pragma unroll
    for (int kk = 0; kk < 16; kk++) {
      float4 hk;
      hk.x = __shfl(o.x, g0 + kk);
      hk.y = __shfl(o.y, g0 + kk);
      hk.z = __shfl(o.z, g0 + kk);
      hk.w = __shfl(o.w, g0 + kk);
      float4 w0 = *(const float4*)&W3[(kk * 4 + 0) * DH + l4];
      acc.x = fmaf(hk.x, w0.x, acc.x);
      acc.y = fmaf(hk.x, w0.y, acc.y);
      acc.z = fmaf(hk.x, w0.z, acc.z);
      acc.w = fmaf(hk.x, w0.w, acc.w);
      float4 w1 = *(const float4*)&W3[(kk * 4 + 1) * DH + l4];
      acc.x = fmaf(hk.y, w1.x, acc.x);
      acc.y = fmaf(hk.y, w1.y, acc.y);
      acc.z = fmaf(hk.y, w1.z, acc.z);
      acc.w = fmaf(hk.y, w1.w, acc.w);
      float4 w2 = *(const float4*)&W3[(kk * 4 + 2) * DH + l4];
      acc.x = fmaf(hk.z, w2.x, acc.x);
      acc.y = fmaf(hk.z, w2.y, acc.y);
      acc.z = fmaf(hk.z, w2.z, acc.z);
      acc.w = fmaf(hk.z, w2.w, acc.w);
      float4 w3 = *(const float4*)&W3[(kk * 4 + 3) * DH + l4];
      acc.x = fmaf(hk.w, w3.x, acc.x);
      acc.y = fmaf(hk.w, w3.y, acc.y);
      acc.z = fmaf(hk.w, w3.z, acc.z);
      acc.w = fmaf(hk.w, w3.w, acc.w);
    }
    float4 b3v = *(const float4*)&b3[l4];
    float4 w4v = *(const float4*)&W4[l4];
    float t, p = 0.f;
    t = acc.x + b3v.x; t = t > 0.f ? t : 0.f; p += t * w4v.x;
    t = acc.y + b3v.y; t = t > 0.f ? t : 0.f; p += t * w4v.y;
    t = acc.z + b3v.z; t = t > 0.f ? t : 0.f; p += t * w4v.z;
    t = acc.w + b3v.w; t = t > 0.f ? t : 0.f; p += t * w4v.w;
    p += __shfl_xor(p, 1);
    p += __shfl_xor(p, 2);
    p += __shfl_xor(p, 4);
    p += __shfl_xor(p, 8);
    if (l == 0) out[n] = p + b4[0];
  }
}

extern "C" void kernel_launch(void* const* d_in, const int* in_sizes, int n_in,
                              void* d_out, int out_size, void* d_ws, size_t ws_size,
                              hipStream_t stream) {
  const float* x      = (const float*)d_in[0];
  const int*   ei     = (const int*)d_in[1];
  const float* ea     = (const float*)d_in[2];
  const float* l1_Wl  = (const float*)d_in[3];
  const float* l1_bl  = (const float*)d_in[4];
  const float* l1_Wr  = (const float*)d_in[5];
  const float* l1_br  = (const float*)d_in[6];
  const float* l1_We  = (const float*)d_in[7];
  const float* l1_att = (const float*)d_in[8];
  const float* l1_bias= (const float*)d_in[9];
  const float* l2_Wl  = (const float*)d_in[10];
  const float* l2_bl  = (const float*)d_in[11];
  const float* l2_Wr  = (const float*)d_in[12];
  const float* l2_br  = (const float*)d_in[13];
  const float* l2_We  = (const float*)d_in[14];
  const float* l2_att = (const float*)d_in[15];
  const float* l2_bias= (const float*)d_in[16];
  const float* W3     = (const float*)d_in[17];
  const float* b3     = (const float*)d_in[18];
  const float* W4     = (const float*)d_in[19];
  const float* b4     = (const float*)d_in[20];
  float* out = (float*)d_out;

  float*    ws     = (float*)d_ws;
  float*    sum    = ws;                        // 256 floats (only [0] used)
  float*    xl     = ws + 256;                  // NN*DH
  float*    xr     = xl + NN * DH;              // NN*DH
  float*    h      = xr + NN * DH;              // NN*DH
  int2*     csr    = (int2*)(h + NN * DH);      // ETOT int2 (8B aligned)
  unsigned* rowptr = (unsigned*)(csr + ETOT);   // NN+1 (+3 pad for alignment)
  unsigned* wptr   = rowptr + NN + 4;           // NN   (16B aligned)
  unsigned* deg    = wptr + NN;                 // NN   (16B aligned)
  unsigned* bsum   = deg + NN;                  // NB, padded to 128 uints
  unsigned short* wf1h = (unsigned short*)(bsum + 128);  // 8*9*64*8 = 36864
  unsigned short* wf1l = wf1h + 36864;
  unsigned short* wf2h = wf1l + 36864;          // 8*2*64*8 = 8192
  unsigned short* wf2l = wf2h + 8192;

  const int B = 256;
  const int mm_blocks   = (NN + 63) / 64;                 // 1563 (64 rows/block)
  const int shard_blocks = NSHARD * ((ETOT + EPB - 1) / EPB);  // 8 * 831 = 6648
  const int attn_blocks = (NN * 16) / B;                  // 6250

  // ---- graph preprocessing + weight repack (independent of each other) ----
  hipMemsetAsync(sum, 0, 256 * sizeof(float), stream);
  hipMemsetAsync(deg, 0, NN * sizeof(unsigned), stream);
  k_wprep<DIN><<<(8 * 9 * 64 + B - 1) / B, B, 0, stream>>>(l1_Wl, l1_Wr, wf1h, wf1l);
  k_wprep<DH><<<(8 * 2 * 64 + B - 1) / B, B, 0, stream>>>(l2_Wl, l2_Wr, wf2h, wf2l);
  k_mean<<<256, B, 0, stream>>>(ea, sum);
  k_hist<<<shard_blocks, B, 0, stream>>>(ei, deg);
  k_bsum<<<NB, B, 0, stream>>>(deg, bsum);
  k_sscan<<<1, 128, 0, stream>>>(bsum, rowptr);
  k_scan2<<<NB, B, 0, stream>>>(deg, bsum, rowptr, wptr);
  k_scatter<<<shard_blocks, B, 0, stream>>>(ei, ea, sum, wptr, csr);

  // ---- layer 1 ----
  k_mm<DIN><<<mm_blocks, 512, 0, stream>>>(x, wf1h, wf1l, l1_bl, l1_br, xl, xr);
  k_attn<false><<<attn_blocks, B, 0, stream>>>(rowptr, csr, xl, xr, l1_We, l1_att,
                                               l1_bias, h, W3, b3, W4, b4, out);

  // ---- layer 2 + head (fused) ----
  k_mm<DH><<<mm_blocks, 512, 0, stream>>>(h, wf2h, wf2l, l2_bl, l2_br, xl, xr);
  k_attn<true><<<attn_blocks, B, 0, stream>>>(rowptr, csr, xl, xr, l2_We, l2_att,
                                              l2_bias, h, W3, b3, W4, b4, out);
}